// Round 12
// baseline (4308.141 us; speedup 1.0000x reference)
//
#include <hip/hip_runtime.h>
#include <hip/hip_bf16.h>
#include <cstddef>
#include <cstdint>

// ---------------------------------------------------------------------------
// DeBERTa forward, MI355X. Round 11: r10 + (a) T14 reg-prefetch of the QP/KP
// HBM streams in flash_attn (K/V stay sync; 4 blocks/CU kept), (b) O-proj
// split-K x2 with combine_ln-fused bias+residual+LN2 (ln2 dispatch deleted).
// B=8 S=512 HID=768 L=12 NH=12 D=64 FF=3072 2M=1024
// ---------------------------------------------------------------------------

constexpr int B   = 8;
constexpr int S   = 512;
constexpr int HID = 768;
constexpr int L   = 12;
constexpr int NH  = 12;
constexpr int D   = 64;
constexpr int FF  = 3072;
constexpr int M2  = 1024;          // 2*M
constexpr int NTOK = B * S;        // 4096

using f32x4 = __attribute__((ext_vector_type(4))) float;
using s16x8 = __attribute__((ext_vector_type(8))) short;
typedef unsigned short us;

__device__ inline float wave_sum(float v) {
#pragma unroll
  for (int o = 32; o > 0; o >>= 1) v += __shfl_xor(v, o, 64);
  return v;
}
__device__ inline us f2bf(float f) {
  __hip_bfloat16 h = __float2bfloat16(f);
  return *reinterpret_cast<us*>(&h);
}
__device__ inline float bf2f(us u) {
  union { unsigned int i; float f; } x;
  x.i = ((unsigned int)u) << 16;
  return x.f;
}
// swizzled elem offset into a [rows][64] bf16 tile (128B rows): granule^row&7
__device__ inline int swz8(int row, int g) {
  return row * 64 + ((g ^ (row & 7)) << 3);
}
// scalar element read index for swizzled tile: element c of row r
__device__ inline int swze(int r, int c) {
  return r * 64 + ((((c >> 3) ^ (r & 7)) << 3) | (c & 7));
}
#define GLOAD16(gp, lp)                                                  \
  __builtin_amdgcn_global_load_lds(                                     \
      (const __attribute__((address_space(1))) void*)(gp),              \
      (__attribute__((address_space(3))) void*)(lp), 16, 0, 0)

// ---- embeddings -------------------------------------------------------------
__global__ void embed_kernel(const int* __restrict__ tok,
                             const int* __restrict__ seg,
                             const float* __restrict__ tok_emb,
                             const float* __restrict__ seg_emb,
                             float* __restrict__ x) {
  int row = blockIdx.x;
  int s = row & (S - 1);
  int t = tok[row];
  int sg = seg[row];
  for (int c = threadIdx.x; c < HID; c += blockDim.x) {
    int i = c >> 1;
    float ang = (float)s * powf(10000.0f, -2.0f * (float)i / (float)HID);
    float pe = (c & 1) ? cosf(ang) : sinf(ang);
    x[(size_t)row * HID + c] = tok_emb[(size_t)t * HID + c] + pe
                             + seg_emb[(size_t)sg * HID + c];
  }
}

// ---- layernorm (one wave per row) -------------------------------------------
template <int BF16OUT>
__global__ __launch_bounds__(256)
void ln_kernel(const float* __restrict__ in, void* __restrict__ outp,
               const float* __restrict__ g, const float* __restrict__ b,
               int nrows) {
  int wave = threadIdx.x >> 6, lane = threadIdx.x & 63;
  int row = blockIdx.x * 4 + wave;
  if (row >= nrows) return;
  const float* xr = in + (size_t)row * HID;
  float v[12];
  float s = 0.f;
#pragma unroll
  for (int i = 0; i < 12; i++) { v[i] = xr[lane + i * 64]; s += v[i]; }
  s = wave_sum(s);
  float mu = s * (1.0f / HID);
  float ss = 0.f;
#pragma unroll
  for (int i = 0; i < 12; i++) { float d = v[i] - mu; ss += d * d; }
  ss = wave_sum(ss);
  float inv = rsqrtf(ss * (1.0f / HID) + 1e-5f);
#pragma unroll
  for (int i = 0; i < 12; i++) {
    int c = lane + i * 64;
    float o = (v[i] - mu) * inv * g[c] + b[c];
    if (BF16OUT)
      ((us*)outp)[(size_t)row * HID + c] = f2bf(o);
    else
      ((float*)outp)[(size_t)row * HID + c] = o;
  }
}

// ---- merged weight prep: 6 square transposes + W1 + W2 + rel conv -----------
__global__ __launch_bounds__(256)
void weight_prep(const float* Wq, const float* Wk, const float* Wv,
                 const float* Wo, const float* Wpk, const float* Wpq,
                 const float* W1s, const float* W2s, const float* rel,
                 us* __restrict__ wt6, us* __restrict__ wt1,
                 us* __restrict__ wt2, us* __restrict__ rel16) {
  int bz = blockIdx.x;
  if (bz >= 8064) {                 // rel f32 -> bf16, 4/thread
    int i = (bz - 8064) * 1024 + threadIdx.x * 4;
    f32x4 v = *(const f32x4*)&rel[i];
#pragma unroll
    for (int j = 0; j < 4; j++) rel16[i + j] = f2bf(v[j]);
    return;
  }
  __shared__ float tile[32][33];
  int tx = threadIdx.x & 31, ty = threadIdx.x >> 5;
  const float* src;
  us* dst;
  int N, K, nt, kt;
  if (bz < 3456) {                  // 6 square [HID,HID]
    int z = bz / 576, r = bz % 576;
    const float* srcs[6] = {Wq, Wk, Wv, Wo, Wpk, Wpq};
    src = srcs[z];
    dst = wt6 + (size_t)z * HID * HID;
    N = HID; K = HID;
    nt = (r % 24) * 32; kt = (r / 24) * 32;
  } else if (bz < 5760) {           // W1 [768,3072] -> [3072,768]
    int r = bz - 3456;
    src = W1s; dst = wt1; N = FF; K = HID;
    nt = (r % 96) * 32; kt = (r / 96) * 32;
  } else {                          // W2 [3072,768] -> [768,3072]
    int r = bz - 5760;
    src = W2s; dst = wt2; N = HID; K = FF;
    nt = (r % 24) * 32; kt = (r / 24) * 32;
  }
#pragma unroll
  for (int i = 0; i < 4; i++)
    tile[ty + i * 8][tx] = src[(size_t)(kt + ty + i * 8) * N + nt + tx];
  __syncthreads();
#pragma unroll
  for (int i = 0; i < 4; i++)
    dst[(size_t)(nt + ty + i * 8) * K + kt + tx] = f2bf(tile[tx][ty + i * 8]);
}

__global__ void concat_bias(const float* __restrict__ bq,
                            const float* __restrict__ bk,
                            const float* __restrict__ bv,
                            float* __restrict__ bqkv) {
  int i = blockIdx.x * 256 + threadIdx.x;
  if (i >= L * 2304) return;
  int l = i / 2304, c = i % 2304;
  float v = (c < 768) ? bq[l * 768 + c]
          : (c < 1536) ? bk[l * 768 + c - 768] : bv[l * 768 + c - 1536];
  bqkv[i] = v;
}

// ---- bf16 MFMA GEMM, 128xTN tile, optional split-K partial ------------------
template <int TN, int OUT_BF16, int GELU, int PARTIAL>
__global__ __launch_bounds__(256)
void mfma_gemm(const us* __restrict__ A, const us* __restrict__ Bt,
               const float* __restrict__ bias, const float* __restrict__ res,
               void* __restrict__ C, int Mr, int K, int N, int Kc) {
  constexpr int NW = TN / 32;
  __shared__ us As[128 * 32];
  __shared__ us Bs[TN * 32];
  int t = threadIdx.x, wave = t >> 6, lane = t & 63;
  int r0 = blockIdx.y * 128, n0 = blockIdx.x * TN;
  int kb = blockIdx.z * Kc;
  int wr = (wave >> 1) * 64;
  int wc = (wave & 1) * (TN / 2);

  f32x4 acc[4][NW] = {};
  int srow = lane >> 2, selem = (lane & 3) * 8;

  for (int k0 = kb; k0 < kb + Kc; k0 += 32) {
    __syncthreads();
    {
      const us* gA = A + (size_t)(r0 + wave * 32 + srow) * K + k0 + selem;
      us* lA = &As[(wave * 32) * 32];
      GLOAD16(gA, lA);
      GLOAD16(gA + (size_t)16 * K, lA + 16 * 32);
      if (TN == 128) {
        const us* gB = Bt + (size_t)(n0 + wave * 32 + srow) * K + k0 + selem;
        us* lB = &Bs[(wave * 32) * 32];
        GLOAD16(gB, lB);
        GLOAD16(gB + (size_t)16 * K, lB + 16 * 32);
      } else {
        const us* gB = Bt + (size_t)(n0 + wave * 16 + srow) * K + k0 + selem;
        GLOAD16(gB, &Bs[(wave * 16) * 32]);
      }
    }
    __syncthreads();

    s16x8 af[4], bf[NW];
#pragma unroll
    for (int m = 0; m < 4; m++)
      af[m] = *(const s16x8*)&As[(wr + m * 16 + (lane & 15)) * 32 + (lane >> 4) * 8];
#pragma unroll
    for (int n = 0; n < NW; n++)
      bf[n] = *(const s16x8*)&Bs[(wc + n * 16 + (lane & 15)) * 32 + (lane >> 4) * 8];
#pragma unroll
    for (int m = 0; m < 4; m++)
#pragma unroll
      for (int n = 0; n < NW; n++)
        acc[m][n] = __builtin_amdgcn_mfma_f32_16x16x32_bf16(af[m], bf[n],
                                                            acc[m][n], 0, 0, 0);
  }

  if (PARTIAL) {
    float* Cp = (float*)C + (size_t)blockIdx.z * Mr * N;
#pragma unroll
    for (int n = 0; n < NW; n++) {
      int c = n0 + wc + n * 16 + (lane & 15);
#pragma unroll
      for (int m = 0; m < 4; m++) {
        int rb = r0 + wr + m * 16 + ((lane >> 4) << 2);
#pragma unroll
        for (int j = 0; j < 4; j++)
          Cp[(size_t)(rb + j) * N + c] = acc[m][n][j];
      }
    }
    return;
  }
#pragma unroll
  for (int n = 0; n < NW; n++) {
    int c = n0 + wc + n * 16 + (lane & 15);
    float bv = bias ? bias[c] : 0.f;
#pragma unroll
    for (int m = 0; m < 4; m++) {
      int rb = r0 + wr + m * 16 + ((lane >> 4) << 2);
#pragma unroll
      for (int j = 0; j < 4; j++) {
        int r = rb + j;
        float val = acc[m][n][j] + bv;
        if (GELU) val = 0.5f * val * (1.0f + erff(val * 0.70710678118654752f));
        if (res)  val += res[(size_t)r * N + c];
        if (OUT_BF16)
          ((us*)C)[(size_t)r * N + c] = f2bf(val);
        else
          ((float*)C)[(size_t)r * N + c] = val;
      }
    }
  }
}

// ---- split-K combine + residual + LN ----------------------------------------
template <int LAST>
__global__ __launch_bounds__(256)
void combine_ln(const float* __restrict__ part,   // [2][NTOK][HID]
                float* __restrict__ x, const float* __restrict__ bias,
                const float* __restrict__ g, const float* __restrict__ bb,
                void* __restrict__ outp) {
  int row = blockIdx.x, t = threadIdx.x;
  int wave = t >> 6, lane = t & 63;
  __shared__ float red[4];
  float v[3];
  float s = 0.f;
#pragma unroll
  for (int i = 0; i < 3; i++) {
    int c = t + i * 256;
    size_t idx = (size_t)row * HID + c;
    float val = x[idx] + part[idx] + part[(size_t)NTOK * HID + idx] + bias[c];
    if (!LAST) x[idx] = val;
    v[i] = val;
    s += val;
  }
  s = wave_sum(s);
  if (lane == 0) red[wave] = s;
  __syncthreads();
  float mu = (red[0] + red[1] + red[2] + red[3]) * (1.0f / HID);
  float ss = 0.f;
#pragma unroll
  for (int i = 0; i < 3; i++) { float d = v[i] - mu; ss += d * d; }
  ss = wave_sum(ss);
  __syncthreads();
  if (lane == 0) red[wave] = ss;
  __syncthreads();
  float inv = rsqrtf((red[0] + red[1] + red[2] + red[3]) * (1.0f / HID) + 1e-5f);
#pragma unroll
  for (int i = 0; i < 3; i++) {
    int c = t + i * 256;
    float o = (v[i] - mu) * inv * g[c] + bb[c];
    if (LAST)
      ((float*)outp)[(size_t)row * HID + c] = o;
    else
      ((us*)outp)[(size_t)row * HID + c] = f2bf(o);
  }
}

// ---- V transpose from fused qkv ----------------------------------------------
__global__ __launch_bounds__(256)
void transpose_v(const us* __restrict__ qkv, us* __restrict__ vt) {
  __shared__ us tile[32][34];
  int bh = blockIdx.z;
  int b = bh / NH, h = bh % NH;
  int s0 = blockIdx.x * 32, d0 = blockIdx.y * 32;
  int tx = threadIdx.x & 31, ty = threadIdx.x >> 5;
#pragma unroll
  for (int i = 0; i < 4; i++)
    tile[ty + i * 8][tx] =
        qkv[(size_t)(b * S + s0 + ty + i * 8) * 2304 + 1536 + h * 64 + d0 + tx];
  __syncthreads();
#pragma unroll
  for (int i = 0; i < 4; i++)
    vt[((size_t)bh * 64 + d0 + ty + i * 8) * S + s0 + tx] = tile[tx][ty + i * 8];
}

// ---- QP/KP precompute: banded GEMM with shifted store ------------------------
// z=0: QP[q,j] = Q_q . pk[q+1+j]   z=1: KP[k,j] = K_k . pq[k+1+j]
__global__ __launch_bounds__(256)
void qpkp_kernel(const us* __restrict__ qkv, const us* __restrict__ pkq,
                 us* __restrict__ QP, us* __restrict__ KP) {
  __shared__ us As[64 * 64];   // A tile (swz)
  __shared__ us Bs[64 * 64];   // B chunk (swz)
  int t = threadIdx.x, wave = t >> 6, lane = t & 63;
  int l15 = lane & 15, l4 = lane >> 4;
  int t0 = blockIdx.x * 64;
  int bh = blockIdx.y;              // 0..95
  int b = bh / NH, h = bh % NH;
  int z = blockIdx.z;
  int zoff = z * 768;
  us* outp = (z ? KP : QP) + ((size_t)bh * 512 + t0) * 512;

  // stage A (64 rows of Q or K for this head)
#pragma unroll
  for (int i = 0; i < 2; i++) {
    int c = t + i * 256;
    int r = c >> 3, g = c & 7;
    *(s16x8*)&As[swz8(r, g)] =
        *(const s16x8*)&qkv[(size_t)(b * S + t0 + r) * 2304 + zoff + h * 64 + g * 8];
  }

  s16x8 af[2];
  for (int c = 0; c < 9; c++) {
    // stage B chunk: pk/pq rows t0+1+c*64 .. +63 (clamped; clamped rows unused)
#pragma unroll
    for (int i = 0; i < 2; i++) {
      int cc = t + i * 256;
      int rr = cc >> 3, g = cc & 7;
      int rb = t0 + 1 + c * 64 + rr;
      rb = rb > M2 - 1 ? M2 - 1 : rb;
      *(s16x8*)&Bs[swz8(rr, g)] =
          *(const s16x8*)&pkq[(size_t)rb * 1536 + zoff + h * 64 + g * 8];
    }
    __syncthreads();
    if (c == 0) {
#pragma unroll
      for (int ks = 0; ks < 2; ks++)
        af[ks] = *(const s16x8*)&As[swz8(wave * 16 + l15, ks * 4 + l4)];
    }
    f32x4 acc[4] = {};
#pragma unroll
    for (int ks = 0; ks < 2; ks++)
#pragma unroll
      for (int n = 0; n < 4; n++) {
        s16x8 bf = *(const s16x8*)&Bs[swz8(n * 16 + l15, ks * 4 + l4)];
        acc[n] = __builtin_amdgcn_mfma_f32_16x16x32_bf16(af[ks], bf, acc[n], 0, 0, 0);
      }
    // shifted store: out[row=iq][j=rc'-iq] for 0<=j<512
#pragma unroll
    for (int n = 0; n < 4; n++) {
      int rcp = c * 64 + n * 16 + l15;
#pragma unroll
      for (int jj = 0; jj < 4; jj++) {
        int iq = wave * 16 + (l4 << 2) + jj;
        int j = rcp - iq;
        if ((unsigned)j < 512u)
          outp[(size_t)iq * 512 + j] = f2bf(acc[n][jj]);
      }
    }
    __syncthreads();
  }
}

// ---- flash attention v6: table scores + T14 reg-prefetch of QP/KP streams ----
// scores[q,k] = (c2c + QP[q,511-k] + KP[k,511-q]) * scale, masked.
// QP/KP (read-once HBM streams) prefetched into regs one tile ahead; K/V
// (L2-resident) staged synchronously at tile tail. 40KB LDS -> 4 blocks/CU.
__global__ __launch_bounds__(256, 4)
void flash_attn(const us* __restrict__ qkv,
                const us* __restrict__ QP,    // [96*512][512]
                const us* __restrict__ KP,
                const us* __restrict__ vt,    // [B*NH*64][S]
                const int* __restrict__ tok,
                us* __restrict__ ctx) {
  __shared__ us Ks[4096];    // K tile (swz)
  __shared__ us Vs[4096];    // V^T tile (swz)
  __shared__ us QPs[4096];   // QP slab tile (swz)
  __shared__ us KPs[4096];   // KP slab tile (swz)
  __shared__ us Ps[4096];    // P (swz)

  int t = threadIdx.x, wave = t >> 6, lane = t & 63;
  int bh = blockIdx.y;
  int b = bh / NH, h = bh % NH;
  int q0 = blockIdx.x * 64;
  int l15 = lane & 15, l4 = lane >> 4;
  const float scale = 0.07216878364870323f;   // 1/sqrt(3*64)

  // staging coords for this thread (2 chunks x (row, granule))
  int sr0 = t >> 3, sg0 = t & 7;              // chunk 0: rows 0..31
  int sr1 = sr0 + 32;                         // chunk 1: rows 32..63

  // persistent Q fragments (wave's 16 q-rows)
  s16x8 qf[2];
#pragma unroll
  for (int ks = 0; ks < 2; ks++)
    qf[ks] = *(const s16x8*)&qkv[(size_t)(b * S + q0 + wave * 16 + l15) * 2304
                                 + h * 64 + ks * 32 + l4 * 8];

  // ---- prologue: stage all 4 tiles for k0 = 0 ----
  {
    *(s16x8*)&Ks[swz8(sr0, sg0)] =
        *(const s16x8*)&qkv[(size_t)(b * S + sr0) * 2304 + 768 + h * 64 + sg0 * 8];
    *(s16x8*)&Ks[swz8(sr1, sg0)] =
        *(const s16x8*)&qkv[(size_t)(b * S + sr1) * 2304 + 768 + h * 64 + sg0 * 8];
    *(s16x8*)&Vs[swz8(sr0, sg0)] =
        *(const s16x8*)&vt[((size_t)bh * 64 + sr0) * S + sg0 * 8];
    *(s16x8*)&Vs[swz8(sr1, sg0)] =
        *(const s16x8*)&vt[((size_t)bh * 64 + sr1) * S + sg0 * 8];
    *(s16x8*)&QPs[swz8(sr0, sg0)] =
        *(const s16x8*)&QP[((size_t)bh * 512 + q0 + sr0) * 512 + 448 + sg0 * 8];
    *(s16x8*)&QPs[swz8(sr1, sg0)] =
        *(const s16x8*)&QP[((size_t)bh * 512 + q0 + sr1) * 512 + 448 + sg0 * 8];
    *(s16x8*)&KPs[swz8(sr0, sg0)] =
        *(const s16x8*)&KP[((size_t)bh * 512 + sr0) * 512 + (448 - q0) + sg0 * 8];
    *(s16x8*)&KPs[swz8(sr1, sg0)] =
        *(const s16x8*)&KP[((size_t)bh * 512 + sr1) * 512 + (448 - q0) + sg0 * 8];
  }
  __syncthreads();                                    // tile 0 visible

  float m[4], l[4];
  f32x4 accO[4];
#pragma unroll
  for (int j = 0; j < 4; j++) { m[j] = -1e30f; l[j] = 0.f; }
#pragma unroll
  for (int n = 0; n < 4; n++) accO[n] = (f32x4){0.f, 0.f, 0.f, 0.f};

  for (int k0 = 0; k0 < S; k0 += 64) {
    int k0n = k0 + 64;
    bool pf = (k0n < S);

    // ---- T14: issue next tile's QP/KP stream loads into regs ----
    s16x8 pfQ0, pfQ1, pfK0, pfK1;
    if (pf) {
      pfQ0 = *(const s16x8*)&QP[((size_t)bh * 512 + q0 + sr0) * 512 + (448 - k0n) + sg0 * 8];
      pfQ1 = *(const s16x8*)&QP[((size_t)bh * 512 + q0 + sr1) * 512 + (448 - k0n) + sg0 * 8];
      pfK0 = *(const s16x8*)&KP[((size_t)bh * 512 + k0n + sr0) * 512 + (448 - q0) + sg0 * 8];
      pfK1 = *(const s16x8*)&KP[((size_t)bh * 512 + k0n + sr1) * 512 + (448 - q0) + sg0 * 8];
    }

    // ---- c2c MFMAs ----
    f32x4 c2c[4] = {};
#pragma unroll
    for (int ks = 0; ks < 2; ks++) {
      int g = ks * 4 + l4;
#pragma unroll
      for (int n = 0; n < 4; n++) {
        s16x8 bk = *(const s16x8*)&Ks[swz8(n * 16 + l15, g)];
        c2c[n] = __builtin_amdgcn_mfma_f32_16x16x32_bf16(qf[ks], bk, c2c[n], 0, 0, 0);
      }
    }

    // ---- score assembly + online softmax ----
    float p[4][4];
    float rmax[4];
#pragma unroll
    for (int j = 0; j < 4; j++) rmax[j] = -1e30f;
#pragma unroll
    for (int n = 0; n < 4; n++) {
      int ik = n * 16 + l15;
      bool msk = (tok[b * S + k0 + ik] == 0);
      int ccp = 63 - ik;             // QPs col for this k
#pragma unroll
      for (int j = 0; j < 4; j++) {
        int iq = wave * 16 + (l4 << 2) + j;
        float sc = c2c[n][j]
                 + bf2f(QPs[swze(iq, ccp)])
                 + bf2f(KPs[swze(ik, 63 - iq)]);
        sc *= scale;
        if (msk) sc = -1e9f;
        p[n][j] = sc;
        rmax[j] = fmaxf(rmax[j], sc);
      }
    }
#pragma unroll
    for (int o = 8; o > 0; o >>= 1)
#pragma unroll
      for (int j = 0; j < 4; j++)
        rmax[j] = fmaxf(rmax[j], __shfl_xor(rmax[j], o, 64));
    float al[4];
#pragma unroll
    for (int j = 0; j < 4; j++) {
      float mn = fmaxf(m[j], rmax[j]);
      al[j] = __expf(m[j] - mn);
      m[j] = mn;
    }
    float rs[4] = {0.f, 0.f, 0.f, 0.f};
#pragma unroll
    for (int n = 0; n < 4; n++)
#pragma unroll
      for (int j = 0; j < 4; j++) {
        p[n][j] = __expf(p[n][j] - m[j]);
        rs[j] += p[n][j];
      }
#pragma unroll
    for (int o = 8; o > 0; o >>= 1)
#pragma unroll
      for (int j = 0; j < 4; j++) rs[j] += __shfl_xor(rs[j], o, 64);
#pragma unroll
    for (int j = 0; j < 4; j++) l[j] = l[j] * al[j] + rs[j];
#pragma unroll
    for (int n = 0; n < 4; n++)
#pragma unroll
      for (int j = 0; j < 4; j++) accO[n][j] *= al[j];

    // ---- P -> Ps ----
    {
      int rw = wave * 16 + (l4 << 2);
#pragma unroll
      for (int n = 0; n < 4; n++)
#pragma unroll
        for (int j = 0; j < 4; j++)
          Ps[swze(rw + j, n * 16 + l15)] = f2bf(p[n][j]);
    }
    __syncthreads();                                  // (2) P visible

    // ---- PV: accO += P @ V ----
#pragma unroll
    for (int ks = 0; ks < 2; ks++) {
      int g = ks * 4 + l4;
      s16x8 ap = *(const s16x8*)&Ps[swz8(wave * 16 + l15, g)];
#pragma unroll
      for (int n = 0; n < 4; n++) {
        s16x8 bv2 = *(const s16x8*)&Vs[swz8(n * 16 + l15, g)];
        accO[n] = __builtin_amdgcn_mfma_f32_16x16x32_bf16(ap, bv2, accO[n], 0, 0, 0);
      }
    }
    __syncthreads();                                  // (3) all reads done

    // ---- tail staging for k0n: prefetched QP/KP + sync K/V (L2-hot) ----
    if (pf) {
      *(s16x8*)&QPs[swz8(sr0, sg0)] = pfQ0;
      *(s16x8*)&QPs[swz8(sr1, sg0)] = pfQ1;
      *(s16x8*)&KPs[swz8(sr0, sg0)] = pfK0;
      *(s16x8*)&KPs[swz8(sr1, sg0)] = pfK1;
      *(s16x8*)&Ks[swz8(sr0, sg0)] =
          *(const s16x8*)&qkv[(size_t)(b * S + k0n + sr0) * 2304 + 768 + h * 64 + sg0 * 8];
      *(s16x8*)&Ks[swz8(sr1, sg0)] =
          *(const s16x8*)&qkv[(size_t)(b * S + k0n + sr1) * 2304 + 768 + h * 64 + sg0 * 8];
      *(s16x8*)&Vs[swz8(sr0, sg0)] =
          *(const s16x8*)&vt[((size_t)bh * 64 + sr0) * S + k0n + sg0 * 8];
      *(s16x8*)&Vs[swz8(sr1, sg0)] =
          *(const s16x8*)&vt[((size_t)bh * 64 + sr1) * S + k0n + sg0 * 8];
      __syncthreads();                                // (1) next tile visible
    }
  }

  // ---- epilogue: O = accO / l ----
#pragma unroll
  for (int n = 0; n < 4; n++) {
    int dd = h * 64 + n * 16 + l15;
#pragma unroll
    for (int j = 0; j < 4; j++) {
      int iq = q0 + wave * 16 + (l4 << 2) + j;
      ctx[(size_t)(b * S + iq) * HID + dd] = f2bf(accO[n][j] / l[j]);
    }
  }
}

// ---------------------------------------------------------------------------
extern "C" void kernel_launch(void* const* d_in, const int* in_sizes, int n_in,
                              void* d_out, int out_size, void* d_ws,
                              size_t ws_size, hipStream_t stream) {
  (void)in_sizes; (void)n_in; (void)out_size; (void)ws_size;
  const int*   tok     = (const int*)d_in[0];
  const int*   seg     = (const int*)d_in[1];
  const float* tok_emb = (const float*)d_in[2];
  const float* seg_emb = (const float*)d_in[3];
  const float* Wq  = (const float*)d_in[4];
  const float* bq  = (const float*)d_in[5];
  const float* Wk  = (const float*)d_in[6];
  const float* bk  = (const float*)d_in[7];
  const float* Wv  = (const float*)d_in[8];
  const float* bv  = (const float*)d_in[9];
  const float* Wo  = (const float*)d_in[10];
  const float* bo  = (const float*)d_in[11];
  const float* Wpk = (const float*)d_in[12];
  const float* Wpq = (const float*)d_in[13];
  const float* rel = (const float*)d_in[14];
  const float* ln1g = (const float*)d_in[15];
  const float* ln1b = (const float*)d_in[16];
  const float* ln2g = (const float*)d_in[17];
  const float* ln2b = (const float*)d_in[18];
  const float* W1  = (const float*)d_in[19];
  const float* b1  = (const float*)d_in[20];
  const float* W2  = (const float*)d_in[21];
  const float* b2  = (const float*)d_in[22];
  const float* lnfg = (const float*)d_in[23];
  const float* lnfb = (const float*)d_in[24];
  float* out = (float*)d_out;

  // ---- workspace layout (~281 MB of ~528 MB) ----
  char* base = (char*)d_ws;
  size_t off = 0;
  auto alloc = [&](size_t bytes) -> void* {
    void* p = base + off;
    off += (bytes + 255) & ~(size_t)255;
    return p;
  };
  const size_t XSZ = (size_t)NTOK * HID;
  float* x = (float*)alloc(XSZ * 4);
  us* qkv16 = (us*)alloc((size_t)NTOK * 2304 * 2);
  us* pkq16 = (us*)alloc((size_t)M2 * 1536 * 2);
  us* vt16  = (us*)alloc(XSZ * 2);
  us* act16 = (us*)alloc(XSZ * 2);
  us* ff16  = (us*)alloc((size_t)NTOK * FF * 2);
  us* rel16 = (us*)alloc((size_t)M2 * HID * 2);
  us* wt6   = (us*)alloc((size_t)6 * HID * HID * 2);
  us* wt1   = (us*)alloc((size_t)HID * FF * 2);
  us* wt2   = (us*)alloc((size_t)HID * FF * 2);
  float* skbuf = (float*)alloc((size_t)2 * NTOK * HID * 4);
  float* bqkv  = (float*)alloc((size_t)L * 2304 * 4);
  us* QP = (us*)alloc((size_t)B * NH * S * 512 * 2);   // 50.33 MB
  us* KP = (us*)alloc((size_t)B * NH * S * 512 * 2);   // 50.33 MB

  const size_t WSQ = (size_t)HID * HID;

  embed_kernel<<<NTOK, 256, 0, stream>>>(tok, seg, tok_emb, seg_emb, x);
  concat_bias<<<(L * 2304 + 255) / 256, 256, 0, stream>>>(bq, bk, bv, bqkv);
  ln_kernel<1><<<NTOK / 4, 256, 0, stream>>>(x, act16, ln1g, ln1b, NTOK);

  for (int l = 0; l < L; l++) {
    // ---- merged weight prep (slots: 0=q 1=k 2=v 3=o 4=pk 5=pq) ----
    weight_prep<<<8832, 256, 0, stream>>>(
        Wq + l * WSQ, Wk + l * WSQ, Wv + l * WSQ, Wo + l * WSQ,
        Wpk + l * WSQ, Wpq + l * WSQ, W1 + (size_t)l * HID * FF,
        W2 + (size_t)l * FF * HID, rel + (size_t)l * M2 * HID,
        wt6, wt1, wt2, rel16);

    // ---- attention ----
    mfma_gemm<128, 1, 0, 0><<<dim3(2304 / 128, NTOK / 128, 1), 256, 0, stream>>>(
        act16, wt6, bqkv + l * 2304, nullptr, qkv16, NTOK, HID, 2304, HID);
    mfma_gemm<64, 1, 0, 0><<<dim3(1536 / 64, M2 / 128, 1), 256, 0, stream>>>(
        rel16, wt6 + 4 * WSQ, nullptr, nullptr, pkq16, M2, HID, 1536, HID);
    transpose_v<<<dim3(S / 32, D / 32, B * NH), 256, 0, stream>>>(qkv16, vt16);
    qpkp_kernel<<<dim3(S / 64, B * NH, 2), 256, 0, stream>>>(
        qkv16, pkq16, QP, KP);
    flash_attn<<<dim3(S / 64, B * NH), 256, 0, stream>>>(
        qkv16, QP, KP, vt16, tok, act16);

    // ---- O-proj: split-K x2 partials + fused (bias + residual + LN2) ----
    mfma_gemm<64, 0, 0, 1><<<dim3(HID / 64, NTOK / 128, 2), 256, 0, stream>>>(
        act16, wt6 + 3 * WSQ, nullptr, nullptr, skbuf, NTOK, HID, HID, HID / 2);
    combine_ln<0><<<NTOK, 256, 0, stream>>>(
        skbuf, x, bo + l * HID, ln2g + l * HID, ln2b + l * HID, act16);

    // ---- feedforward ----
    mfma_gemm<128, 1, 1, 0><<<dim3(FF / 128, NTOK / 128, 1), 256, 0, stream>>>(
        act16, wt1, b1 + l * FF, nullptr, ff16, NTOK, HID, FF, HID);
    mfma_gemm<64, 0, 0, 1><<<dim3(HID / 64, NTOK / 128, 2), 256, 0, stream>>>(
        ff16, wt2, nullptr, nullptr, skbuf, NTOK, FF, HID, FF / 2);
    if (l < L - 1) {
      combine_ln<0><<<NTOK, 256, 0, stream>>>(
          skbuf, x, b2 + l * HID, ln1g + (l + 1) * HID, ln1b + (l + 1) * HID,
          act16);
    } else {
      combine_ln<1><<<NTOK, 256, 0, stream>>>(
          skbuf, x, b2 + l * HID, lnfg, lnfb, out);
    }
  }
}

// Round 13
// 4303.632 us; speedup vs baseline: 1.0010x; 1.0010x over previous
//
#include <hip/hip_runtime.h>
#include <hip/hip_bf16.h>
#include <cstddef>
#include <cstdint>

// ---------------------------------------------------------------------------
// DeBERTa forward, MI355X. Round 11: r10 + (a) T14 reg-prefetch of the QP/KP
// HBM streams in flash_attn (K/V stay sync; 4 blocks/CU kept), (b) O-proj
// split-K x2 with combine_ln-fused bias+residual+LN2 (ln2 dispatch deleted).
// B=8 S=512 HID=768 L=12 NH=12 D=64 FF=3072 2M=1024
// ---------------------------------------------------------------------------

constexpr int B   = 8;
constexpr int S   = 512;
constexpr int HID = 768;
constexpr int L   = 12;
constexpr int NH  = 12;
constexpr int D   = 64;
constexpr int FF  = 3072;
constexpr int M2  = 1024;          // 2*M
constexpr int NTOK = B * S;        // 4096

using f32x4 = __attribute__((ext_vector_type(4))) float;
using s16x8 = __attribute__((ext_vector_type(8))) short;
typedef unsigned short us;

__device__ inline float wave_sum(float v) {
#pragma unroll
  for (int o = 32; o > 0; o >>= 1) v += __shfl_xor(v, o, 64);
  return v;
}
__device__ inline us f2bf(float f) {
  __hip_bfloat16 h = __float2bfloat16(f);
  return *reinterpret_cast<us*>(&h);
}
__device__ inline float bf2f(us u) {
  union { unsigned int i; float f; } x;
  x.i = ((unsigned int)u) << 16;
  return x.f;
}
// swizzled elem offset into a [rows][64] bf16 tile (128B rows): granule^row&7
__device__ inline int swz8(int row, int g) {
  return row * 64 + ((g ^ (row & 7)) << 3);
}
// scalar element read index for swizzled tile: element c of row r
__device__ inline int swze(int r, int c) {
  return r * 64 + ((((c >> 3) ^ (r & 7)) << 3) | (c & 7));
}
#define GLOAD16(gp, lp)                                                  \
  __builtin_amdgcn_global_load_lds(                                     \
      (const __attribute__((address_space(1))) void*)(gp),              \
      (__attribute__((address_space(3))) void*)(lp), 16, 0, 0)

// ---- embeddings -------------------------------------------------------------
__global__ void embed_kernel(const int* __restrict__ tok,
                             const int* __restrict__ seg,
                             const float* __restrict__ tok_emb,
                             const float* __restrict__ seg_emb,
                             float* __restrict__ x) {
  int row = blockIdx.x;
  int s = row & (S - 1);
  int t = tok[row];
  int sg = seg[row];
  for (int c = threadIdx.x; c < HID; c += blockDim.x) {
    int i = c >> 1;
    float ang = (float)s * powf(10000.0f, -2.0f * (float)i / (float)HID);
    float pe = (c & 1) ? cosf(ang) : sinf(ang);
    x[(size_t)row * HID + c] = tok_emb[(size_t)t * HID + c] + pe
                             + seg_emb[(size_t)sg * HID + c];
  }
}

// ---- layernorm (one wave per row) -------------------------------------------
template <int BF16OUT>
__global__ __launch_bounds__(256)
void ln_kernel(const float* __restrict__ in, void* __restrict__ outp,
               const float* __restrict__ g, const float* __restrict__ b,
               int nrows) {
  int wave = threadIdx.x >> 6, lane = threadIdx.x & 63;
  int row = blockIdx.x * 4 + wave;
  if (row >= nrows) return;
  const float* xr = in + (size_t)row * HID;
  float v[12];
  float s = 0.f;
#pragma unroll
  for (int i = 0; i < 12; i++) { v[i] = xr[lane + i * 64]; s += v[i]; }
  s = wave_sum(s);
  float mu = s * (1.0f / HID);
  float ss = 0.f;
#pragma unroll
  for (int i = 0; i < 12; i++) { float d = v[i] - mu; ss += d * d; }
  ss = wave_sum(ss);
  float inv = rsqrtf(ss * (1.0f / HID) + 1e-5f);
#pragma unroll
  for (int i = 0; i < 12; i++) {
    int c = lane + i * 64;
    float o = (v[i] - mu) * inv * g[c] + b[c];
    if (BF16OUT)
      ((us*)outp)[(size_t)row * HID + c] = f2bf(o);
    else
      ((float*)outp)[(size_t)row * HID + c] = o;
  }
}

// ---- merged weight prep: 6 square transposes + W1 + W2 + rel conv -----------
__global__ __launch_bounds__(256)
void weight_prep(const float* Wq, const float* Wk, const float* Wv,
                 const float* Wo, const float* Wpk, const float* Wpq,
                 const float* W1s, const float* W2s, const float* rel,
                 us* __restrict__ wt6, us* __restrict__ wt1,
                 us* __restrict__ wt2, us* __restrict__ rel16) {
  int bz = blockIdx.x;
  if (bz >= 8064) {                 // rel f32 -> bf16, 4/thread
    int i = (bz - 8064) * 1024 + threadIdx.x * 4;
    f32x4 v = *(const f32x4*)&rel[i];
#pragma unroll
    for (int j = 0; j < 4; j++) rel16[i + j] = f2bf(v[j]);
    return;
  }
  __shared__ float tile[32][33];
  int tx = threadIdx.x & 31, ty = threadIdx.x >> 5;
  const float* src;
  us* dst;
  int N, K, nt, kt;
  if (bz < 3456) {                  // 6 square [HID,HID]
    int z = bz / 576, r = bz % 576;
    const float* srcs[6] = {Wq, Wk, Wv, Wo, Wpk, Wpq};
    src = srcs[z];
    dst = wt6 + (size_t)z * HID * HID;
    N = HID; K = HID;
    nt = (r % 24) * 32; kt = (r / 24) * 32;
  } else if (bz < 5760) {           // W1 [768,3072] -> [3072,768]
    int r = bz - 3456;
    src = W1s; dst = wt1; N = FF; K = HID;
    nt = (r % 96) * 32; kt = (r / 96) * 32;
  } else {                          // W2 [3072,768] -> [768,3072]
    int r = bz - 5760;
    src = W2s; dst = wt2; N = HID; K = FF;
    nt = (r % 24) * 32; kt = (r / 24) * 32;
  }
#pragma unroll
  for (int i = 0; i < 4; i++)
    tile[ty + i * 8][tx] = src[(size_t)(kt + ty + i * 8) * N + nt + tx];
  __syncthreads();
#pragma unroll
  for (int i = 0; i < 4; i++)
    dst[(size_t)(nt + ty + i * 8) * K + kt + tx] = f2bf(tile[tx][ty + i * 8]);
}

__global__ void concat_bias(const float* __restrict__ bq,
                            const float* __restrict__ bk,
                            const float* __restrict__ bv,
                            float* __restrict__ bqkv) {
  int i = blockIdx.x * 256 + threadIdx.x;
  if (i >= L * 2304) return;
  int l = i / 2304, c = i % 2304;
  float v = (c < 768) ? bq[l * 768 + c]
          : (c < 1536) ? bk[l * 768 + c - 768] : bv[l * 768 + c - 1536];
  bqkv[i] = v;
}

// ---- bf16 MFMA GEMM, 128xTN tile, optional split-K partial ------------------
template <int TN, int OUT_BF16, int GELU, int PARTIAL>
__global__ __launch_bounds__(256)
void mfma_gemm(const us* __restrict__ A, const us* __restrict__ Bt,
               const float* __restrict__ bias, const float* __restrict__ res,
               void* __restrict__ C, int Mr, int K, int N, int Kc) {
  constexpr int NW = TN / 32;
  __shared__ us As[128 * 32];
  __shared__ us Bs[TN * 32];
  int t = threadIdx.x, wave = t >> 6, lane = t & 63;
  int r0 = blockIdx.y * 128, n0 = blockIdx.x * TN;
  int kb = blockIdx.z * Kc;
  int wr = (wave >> 1) * 64;
  int wc = (wave & 1) * (TN / 2);

  f32x4 acc[4][NW] = {};
  int srow = lane >> 2, selem = (lane & 3) * 8;

  for (int k0 = kb; k0 < kb + Kc; k0 += 32) {
    __syncthreads();
    {
      const us* gA = A + (size_t)(r0 + wave * 32 + srow) * K + k0 + selem;
      us* lA = &As[(wave * 32) * 32];
      GLOAD16(gA, lA);
      GLOAD16(gA + (size_t)16 * K, lA + 16 * 32);
      if (TN == 128) {
        const us* gB = Bt + (size_t)(n0 + wave * 32 + srow) * K + k0 + selem;
        us* lB = &Bs[(wave * 32) * 32];
        GLOAD16(gB, lB);
        GLOAD16(gB + (size_t)16 * K, lB + 16 * 32);
      } else {
        const us* gB = Bt + (size_t)(n0 + wave * 16 + srow) * K + k0 + selem;
        GLOAD16(gB, &Bs[(wave * 16) * 32]);
      }
    }
    __syncthreads();

    s16x8 af[4], bf[NW];
#pragma unroll
    for (int m = 0; m < 4; m++)
      af[m] = *(const s16x8*)&As[(wr + m * 16 + (lane & 15)) * 32 + (lane >> 4) * 8];
#pragma unroll
    for (int n = 0; n < NW; n++)
      bf[n] = *(const s16x8*)&Bs[(wc + n * 16 + (lane & 15)) * 32 + (lane >> 4) * 8];
#pragma unroll
    for (int m = 0; m < 4; m++)
#pragma unroll
      for (int n = 0; n < NW; n++)
        acc[m][n] = __builtin_amdgcn_mfma_f32_16x16x32_bf16(af[m], bf[n],
                                                            acc[m][n], 0, 0, 0);
  }

  if (PARTIAL) {
    float* Cp = (float*)C + (size_t)blockIdx.z * Mr * N;
#pragma unroll
    for (int n = 0; n < NW; n++) {
      int c = n0 + wc + n * 16 + (lane & 15);
#pragma unroll
      for (int m = 0; m < 4; m++) {
        int rb = r0 + wr + m * 16 + ((lane >> 4) << 2);
#pragma unroll
        for (int j = 0; j < 4; j++)
          Cp[(size_t)(rb + j) * N + c] = acc[m][n][j];
      }
    }
    return;
  }
#pragma unroll
  for (int n = 0; n < NW; n++) {
    int c = n0 + wc + n * 16 + (lane & 15);
    float bv = bias ? bias[c] : 0.f;
#pragma unroll
    for (int m = 0; m < 4; m++) {
      int rb = r0 + wr + m * 16 + ((lane >> 4) << 2);
#pragma unroll
      for (int j = 0; j < 4; j++) {
        int r = rb + j;
        float val = acc[m][n][j] + bv;
        if (GELU) val = 0.5f * val * (1.0f + erff(val * 0.70710678118654752f));
        if (res)  val += res[(size_t)r * N + c];
        if (OUT_BF16)
          ((us*)C)[(size_t)r * N + c] = f2bf(val);
        else
          ((float*)C)[(size_t)r * N + c] = val;
      }
    }
  }
}

// ---- split-K combine + residual + LN ----------------------------------------
template <int LAST>
__global__ __launch_bounds__(256)
void combine_ln(const float* __restrict__ part,   // [2][NTOK][HID]
                float* __restrict__ x, const float* __restrict__ bias,
                const float* __restrict__ g, const float* __restrict__ bb,
                void* __restrict__ outp) {
  int row = blockIdx.x, t = threadIdx.x;
  int wave = t >> 6, lane = t & 63;
  __shared__ float red[4];
  float v[3];
  float s = 0.f;
#pragma unroll
  for (int i = 0; i < 3; i++) {
    int c = t + i * 256;
    size_t idx = (size_t)row * HID + c;
    float val = x[idx] + part[idx] + part[(size_t)NTOK * HID + idx] + bias[c];
    if (!LAST) x[idx] = val;
    v[i] = val;
    s += val;
  }
  s = wave_sum(s);
  if (lane == 0) red[wave] = s;
  __syncthreads();
  float mu = (red[0] + red[1] + red[2] + red[3]) * (1.0f / HID);
  float ss = 0.f;
#pragma unroll
  for (int i = 0; i < 3; i++) { float d = v[i] - mu; ss += d * d; }
  ss = wave_sum(ss);
  __syncthreads();
  if (lane == 0) red[wave] = ss;
  __syncthreads();
  float inv = rsqrtf((red[0] + red[1] + red[2] + red[3]) * (1.0f / HID) + 1e-5f);
#pragma unroll
  for (int i = 0; i < 3; i++) {
    int c = t + i * 256;
    float o = (v[i] - mu) * inv * g[c] + bb[c];
    if (LAST)
      ((float*)outp)[(size_t)row * HID + c] = o;
    else
      ((us*)outp)[(size_t)row * HID + c] = f2bf(o);
  }
}

// ---- V transpose from fused qkv ----------------------------------------------
__global__ __launch_bounds__(256)
void transpose_v(const us* __restrict__ qkv, us* __restrict__ vt) {
  __shared__ us tile[32][34];
  int bh = blockIdx.z;
  int b = bh / NH, h = bh % NH;
  int s0 = blockIdx.x * 32, d0 = blockIdx.y * 32;
  int tx = threadIdx.x & 31, ty = threadIdx.x >> 5;
#pragma unroll
  for (int i = 0; i < 4; i++)
    tile[ty + i * 8][tx] =
        qkv[(size_t)(b * S + s0 + ty + i * 8) * 2304 + 1536 + h * 64 + d0 + tx];
  __syncthreads();
#pragma unroll
  for (int i = 0; i < 4; i++)
    vt[((size_t)bh * 64 + d0 + ty + i * 8) * S + s0 + tx] = tile[tx][ty + i * 8];
}

// ---- QP/KP precompute: banded GEMM with shifted store ------------------------
// z=0: QP[q,j] = Q_q . pk[q+1+j]   z=1: KP[k,j] = K_k . pq[k+1+j]
__global__ __launch_bounds__(256)
void qpkp_kernel(const us* __restrict__ qkv, const us* __restrict__ pkq,
                 us* __restrict__ QP, us* __restrict__ KP) {
  __shared__ us As[64 * 64];   // A tile (swz)
  __shared__ us Bs[64 * 64];   // B chunk (swz)
  int t = threadIdx.x, wave = t >> 6, lane = t & 63;
  int l15 = lane & 15, l4 = lane >> 4;
  int t0 = blockIdx.x * 64;
  int bh = blockIdx.y;              // 0..95
  int b = bh / NH, h = bh % NH;
  int z = blockIdx.z;
  int zoff = z * 768;
  us* outp = (z ? KP : QP) + ((size_t)bh * 512 + t0) * 512;

  // stage A (64 rows of Q or K for this head)
#pragma unroll
  for (int i = 0; i < 2; i++) {
    int c = t + i * 256;
    int r = c >> 3, g = c & 7;
    *(s16x8*)&As[swz8(r, g)] =
        *(const s16x8*)&qkv[(size_t)(b * S + t0 + r) * 2304 + zoff + h * 64 + g * 8];
  }

  s16x8 af[2];
  for (int c = 0; c < 9; c++) {
    // stage B chunk: pk/pq rows t0+1+c*64 .. +63 (clamped; clamped rows unused)
#pragma unroll
    for (int i = 0; i < 2; i++) {
      int cc = t + i * 256;
      int rr = cc >> 3, g = cc & 7;
      int rb = t0 + 1 + c * 64 + rr;
      rb = rb > M2 - 1 ? M2 - 1 : rb;
      *(s16x8*)&Bs[swz8(rr, g)] =
          *(const s16x8*)&pkq[(size_t)rb * 1536 + zoff + h * 64 + g * 8];
    }
    __syncthreads();
    if (c == 0) {
#pragma unroll
      for (int ks = 0; ks < 2; ks++)
        af[ks] = *(const s16x8*)&As[swz8(wave * 16 + l15, ks * 4 + l4)];
    }
    f32x4 acc[4] = {};
#pragma unroll
    for (int ks = 0; ks < 2; ks++)
#pragma unroll
      for (int n = 0; n < 4; n++) {
        s16x8 bf = *(const s16x8*)&Bs[swz8(n * 16 + l15, ks * 4 + l4)];
        acc[n] = __builtin_amdgcn_mfma_f32_16x16x32_bf16(af[ks], bf, acc[n], 0, 0, 0);
      }
    // shifted store: out[row=iq][j=rc'-iq] for 0<=j<512
#pragma unroll
    for (int n = 0; n < 4; n++) {
      int rcp = c * 64 + n * 16 + l15;
#pragma unroll
      for (int jj = 0; jj < 4; jj++) {
        int iq = wave * 16 + (l4 << 2) + jj;
        int j = rcp - iq;
        if ((unsigned)j < 512u)
          outp[(size_t)iq * 512 + j] = f2bf(acc[n][jj]);
      }
    }
    __syncthreads();
  }
}

// ---- flash attention v6: table scores + T14 reg-prefetch of QP/KP streams ----
// scores[q,k] = (c2c + QP[q,511-k] + KP[k,511-q]) * scale, masked.
// QP/KP (read-once HBM streams) prefetched into regs one tile ahead; K/V
// (L2-resident) staged synchronously at tile tail. 40KB LDS -> 4 blocks/CU.
__global__ __launch_bounds__(256, 4)
void flash_attn(const us* __restrict__ qkv,
                const us* __restrict__ QP,    // [96*512][512]
                const us* __restrict__ KP,
                const us* __restrict__ vt,    // [B*NH*64][S]
                const int* __restrict__ tok,
                us* __restrict__ ctx) {
  __shared__ us Ks[4096];    // K tile (swz)
  __shared__ us Vs[4096];    // V^T tile (swz)
  __shared__ us QPs[4096];   // QP slab tile (swz)
  __shared__ us KPs[4096];   // KP slab tile (swz)
  __shared__ us Ps[4096];    // P (swz)

  int t = threadIdx.x, wave = t >> 6, lane = t & 63;
  int bh = blockIdx.y;
  int b = bh / NH, h = bh % NH;
  int q0 = blockIdx.x * 64;
  int l15 = lane & 15, l4 = lane >> 4;
  const float scale = 0.07216878364870323f;   // 1/sqrt(3*64)

  // staging coords for this thread (2 chunks x (row, granule))
  int sr0 = t >> 3, sg0 = t & 7;              // chunk 0: rows 0..31
  int sr1 = sr0 + 32;                         // chunk 1: rows 32..63

  // persistent Q fragments (wave's 16 q-rows)
  s16x8 qf[2];
#pragma unroll
  for (int ks = 0; ks < 2; ks++)
    qf[ks] = *(const s16x8*)&qkv[(size_t)(b * S + q0 + wave * 16 + l15) * 2304
                                 + h * 64 + ks * 32 + l4 * 8];

  // ---- prologue: stage all 4 tiles for k0 = 0 ----
  {
    *(s16x8*)&Ks[swz8(sr0, sg0)] =
        *(const s16x8*)&qkv[(size_t)(b * S + sr0) * 2304 + 768 + h * 64 + sg0 * 8];
    *(s16x8*)&Ks[swz8(sr1, sg0)] =
        *(const s16x8*)&qkv[(size_t)(b * S + sr1) * 2304 + 768 + h * 64 + sg0 * 8];
    *(s16x8*)&Vs[swz8(sr0, sg0)] =
        *(const s16x8*)&vt[((size_t)bh * 64 + sr0) * S + sg0 * 8];
    *(s16x8*)&Vs[swz8(sr1, sg0)] =
        *(const s16x8*)&vt[((size_t)bh * 64 + sr1) * S + sg0 * 8];
    *(s16x8*)&QPs[swz8(sr0, sg0)] =
        *(const s16x8*)&QP[((size_t)bh * 512 + q0 + sr0) * 512 + 448 + sg0 * 8];
    *(s16x8*)&QPs[swz8(sr1, sg0)] =
        *(const s16x8*)&QP[((size_t)bh * 512 + q0 + sr1) * 512 + 448 + sg0 * 8];
    *(s16x8*)&KPs[swz8(sr0, sg0)] =
        *(const s16x8*)&KP[((size_t)bh * 512 + sr0) * 512 + (448 - q0) + sg0 * 8];
    *(s16x8*)&KPs[swz8(sr1, sg0)] =
        *(const s16x8*)&KP[((size_t)bh * 512 + sr1) * 512 + (448 - q0) + sg0 * 8];
  }
  __syncthreads();                                    // tile 0 visible

  float m[4], l[4];
  f32x4 accO[4];
#pragma unroll
  for (int j = 0; j < 4; j++) { m[j] = -1e30f; l[j] = 0.f; }
#pragma unroll
  for (int n = 0; n < 4; n++) accO[n] = (f32x4){0.f, 0.f, 0.f, 0.f};

  for (int k0 = 0; k0 < S; k0 += 64) {
    int k0n = k0 + 64;
    bool pf = (k0n < S);

    // ---- T14: issue next tile's QP/KP stream loads into regs ----
    s16x8 pfQ0, pfQ1, pfK0, pfK1;
    if (pf) {
      pfQ0 = *(const s16x8*)&QP[((size_t)bh * 512 + q0 + sr0) * 512 + (448 - k0n) + sg0 * 8];
      pfQ1 = *(const s16x8*)&QP[((size_t)bh * 512 + q0 + sr1) * 512 + (448 - k0n) + sg0 * 8];
      pfK0 = *(const s16x8*)&KP[((size_t)bh * 512 + k0n + sr0) * 512 + (448 - q0) + sg0 * 8];
      pfK1 = *(const s16x8*)&KP[((size_t)bh * 512 + k0n + sr1) * 512 + (448 - q0) + sg0 * 8];
    }

    // ---- c2c MFMAs ----
    f32x4 c2c[4] = {};
#pragma unroll
    for (int ks = 0; ks < 2; ks++) {
      int g = ks * 4 + l4;
#pragma unroll
      for (int n = 0; n < 4; n++) {
        s16x8 bk = *(const s16x8*)&Ks[swz8(n * 16 + l15, g)];
        c2c[n] = __builtin_amdgcn_mfma_f32_16x16x32_bf16(qf[ks], bk, c2c[n], 0, 0, 0);
      }
    }

    // ---- score assembly + online softmax ----
    float p[4][4];
    float rmax[4];
#pragma unroll
    for (int j = 0; j < 4; j++) rmax[j] = -1e30f;
#pragma unroll
    for (int n = 0; n < 4; n++) {
      int ik = n * 16 + l15;
      bool msk = (tok[b * S + k0 + ik] == 0);
      int ccp = 63 - ik;             // QPs col for this k
#pragma unroll
      for (int j = 0; j < 4; j++) {
        int iq = wave * 16 + (l4 << 2) + j;
        float sc = c2c[n][j]
                 + bf2f(QPs[swze(iq, ccp)])
                 + bf2f(KPs[swze(ik, 63 - iq)]);
        sc *= scale;
        if (msk) sc = -1e9f;
        p[n][j] = sc;
        rmax[j] = fmaxf(rmax[j], sc);
      }
    }
#pragma unroll
    for (int o = 8; o > 0; o >>= 1)
#pragma unroll
      for (int j = 0; j < 4; j++)
        rmax[j] = fmaxf(rmax[j], __shfl_xor(rmax[j], o, 64));
    float al[4];
#pragma unroll
    for (int j = 0; j < 4; j++) {
      float mn = fmaxf(m[j], rmax[j]);
      al[j] = __expf(m[j] - mn);
      m[j] = mn;
    }
    float rs[4] = {0.f, 0.f, 0.f, 0.f};
#pragma unroll
    for (int n = 0; n < 4; n++)
#pragma unroll
      for (int j = 0; j < 4; j++) {
        p[n][j] = __expf(p[n][j] - m[j]);
        rs[j] += p[n][j];
      }
#pragma unroll
    for (int o = 8; o > 0; o >>= 1)
#pragma unroll
      for (int j = 0; j < 4; j++) rs[j] += __shfl_xor(rs[j], o, 64);
#pragma unroll
    for (int j = 0; j < 4; j++) l[j] = l[j] * al[j] + rs[j];
#pragma unroll
    for (int n = 0; n < 4; n++)
#pragma unroll
      for (int j = 0; j < 4; j++) accO[n][j] *= al[j];

    // ---- P -> Ps ----
    {
      int rw = wave * 16 + (l4 << 2);
#pragma unroll
      for (int n = 0; n < 4; n++)
#pragma unroll
        for (int j = 0; j < 4; j++)
          Ps[swze(rw + j, n * 16 + l15)] = f2bf(p[n][j]);
    }
    __syncthreads();                                  // (2) P visible

    // ---- PV: accO += P @ V ----
#pragma unroll
    for (int ks = 0; ks < 2; ks++) {
      int g = ks * 4 + l4;
      s16x8 ap = *(const s16x8*)&Ps[swz8(wave * 16 + l15, g)];
#pragma unroll
      for (int n = 0; n < 4; n++) {
        s16x8 bv2 = *(const s16x8*)&Vs[swz8(n * 16 + l15, g)];
        accO[n] = __builtin_amdgcn_mfma_f32_16x16x32_bf16(ap, bv2, accO[n], 0, 0, 0);
      }
    }
    __syncthreads();                                  // (3) all reads done

    // ---- tail staging for k0n: prefetched QP/KP + sync K/V (L2-hot) ----
    if (pf) {
      *(s16x8*)&QPs[swz8(sr0, sg0)] = pfQ0;
      *(s16x8*)&QPs[swz8(sr1, sg0)] = pfQ1;
      *(s16x8*)&KPs[swz8(sr0, sg0)] = pfK0;
      *(s16x8*)&KPs[swz8(sr1, sg0)] = pfK1;
      *(s16x8*)&Ks[swz8(sr0, sg0)] =
          *(const s16x8*)&qkv[(size_t)(b * S + k0n + sr0) * 2304 + 768 + h * 64 + sg0 * 8];
      *(s16x8*)&Ks[swz8(sr1, sg0)] =
          *(const s16x8*)&qkv[(size_t)(b * S + k0n + sr1) * 2304 + 768 + h * 64 + sg0 * 8];
      *(s16x8*)&Vs[swz8(sr0, sg0)] =
          *(const s16x8*)&vt[((size_t)bh * 64 + sr0) * S + k0n + sg0 * 8];
      *(s16x8*)&Vs[swz8(sr1, sg0)] =
          *(const s16x8*)&vt[((size_t)bh * 64 + sr1) * S + k0n + sg0 * 8];
      __syncthreads();                                // (1) next tile visible
    }
  }

  // ---- epilogue: O = accO / l ----
#pragma unroll
  for (int n = 0; n < 4; n++) {
    int dd = h * 64 + n * 16 + l15;
#pragma unroll
    for (int j = 0; j < 4; j++) {
      int iq = q0 + wave * 16 + (l4 << 2) + j;
      ctx[(size_t)(b * S + iq) * HID + dd] = f2bf(accO[n][j] / l[j]);
    }
  }
}

// ---------------------------------------------------------------------------
extern "C" void kernel_launch(void* const* d_in, const int* in_sizes, int n_in,
                              void* d_out, int out_size, void* d_ws,
                              size_t ws_size, hipStream_t stream) {
  (void)in_sizes; (void)n_in; (void)out_size; (void)ws_size;
  const int*   tok     = (const int*)d_in[0];
  const int*   seg     = (const int*)d_in[1];
  const float* tok_emb = (const float*)d_in[2];
  const float* seg_emb = (const float*)d_in[3];
  const float* Wq  = (const float*)d_in[4];
  const float* bq  = (const float*)d_in[5];
  const float* Wk  = (const float*)d_in[6];
  const float* bk  = (const float*)d_in[7];
  const float* Wv  = (const float*)d_in[8];
  const float* bv  = (const float*)d_in[9];
  const float* Wo  = (const float*)d_in[10];
  const float* bo  = (const float*)d_in[11];
  const float* Wpk = (const float*)d_in[12];
  const float* Wpq = (const float*)d_in[13];
  const float* rel = (const float*)d_in[14];
  const float* ln1g = (const float*)d_in[15];
  const float* ln1b = (const float*)d_in[16];
  const float* ln2g = (const float*)d_in[17];
  const float* ln2b = (const float*)d_in[18];
  const float* W1  = (const float*)d_in[19];
  const float* b1  = (const float*)d_in[20];
  const float* W2  = (const float*)d_in[21];
  const float* b2  = (const float*)d_in[22];
  const float* lnfg = (const float*)d_in[23];
  const float* lnfb = (const float*)d_in[24];
  float* out = (float*)d_out;

  // ---- workspace layout (~281 MB of ~528 MB) ----
  char* base = (char*)d_ws;
  size_t off = 0;
  auto alloc = [&](size_t bytes) -> void* {
    void* p = base + off;
    off += (bytes + 255) & ~(size_t)255;
    return p;
  };
  const size_t XSZ = (size_t)NTOK * HID;
  float* x = (float*)alloc(XSZ * 4);
  us* qkv16 = (us*)alloc((size_t)NTOK * 2304 * 2);
  us* pkq16 = (us*)alloc((size_t)M2 * 1536 * 2);
  us* vt16  = (us*)alloc(XSZ * 2);
  us* act16 = (us*)alloc(XSZ * 2);
  us* ff16  = (us*)alloc((size_t)NTOK * FF * 2);
  us* rel16 = (us*)alloc((size_t)M2 * HID * 2);
  us* wt6   = (us*)alloc((size_t)6 * HID * HID * 2);
  us* wt1   = (us*)alloc((size_t)HID * FF * 2);
  us* wt2   = (us*)alloc((size_t)HID * FF * 2);
  float* skbuf = (float*)alloc((size_t)2 * NTOK * HID * 4);
  float* bqkv  = (float*)alloc((size_t)L * 2304 * 4);
  us* QP = (us*)alloc((size_t)B * NH * S * 512 * 2);   // 50.33 MB
  us* KP = (us*)alloc((size_t)B * NH * S * 512 * 2);   // 50.33 MB

  const size_t WSQ = (size_t)HID * HID;

  embed_kernel<<<NTOK, 256, 0, stream>>>(tok, seg, tok_emb, seg_emb, x);
  concat_bias<<<(L * 2304 + 255) / 256, 256, 0, stream>>>(bq, bk, bv, bqkv);
  ln_kernel<1><<<NTOK / 4, 256, 0, stream>>>(x, act16, ln1g, ln1b, NTOK);

  for (int l = 0; l < L; l++) {
    // ---- merged weight prep (slots: 0=q 1=k 2=v 3=o 4=pk 5=pq) ----
    weight_prep<<<8832, 256, 0, stream>>>(
        Wq + l * WSQ, Wk + l * WSQ, Wv + l * WSQ, Wo + l * WSQ,
        Wpk + l * WSQ, Wpq + l * WSQ, W1 + (size_t)l * HID * FF,
        W2 + (size_t)l * FF * HID, rel + (size_t)l * M2 * HID,
        wt6, wt1, wt2, rel16);

    // ---- attention ----
    mfma_gemm<128, 1, 0, 0><<<dim3(2304 / 128, NTOK / 128, 1), 256, 0, stream>>>(
        act16, wt6, bqkv + l * 2304, nullptr, qkv16, NTOK, HID, 2304, HID);
    mfma_gemm<64, 1, 0, 0><<<dim3(1536 / 64, M2 / 128, 1), 256, 0, stream>>>(
        rel16, wt6 + 4 * WSQ, nullptr, nullptr, pkq16, M2, HID, 1536, HID);
    transpose_v<<<dim3(S / 32, D / 32, B * NH), 256, 0, stream>>>(qkv16, vt16);
    qpkp_kernel<<<dim3(S / 64, B * NH, 2), 256, 0, stream>>>(
        qkv16, pkq16, QP, KP);
    flash_attn<<<dim3(S / 64, B * NH), 256, 0, stream>>>(
        qkv16, QP, KP, vt16, tok, act16);

    // ---- O-proj: split-K x2 partials + fused (bias + residual + LN2) ----
    mfma_gemm<64, 0, 0, 1><<<dim3(HID / 64, NTOK / 128, 2), 256, 0, stream>>>(
        act16, wt6 + 3 * WSQ, nullptr, nullptr, skbuf, NTOK, HID, HID, HID / 2);
    combine_ln<0><<<NTOK, 256, 0, stream>>>(
        skbuf, x, bo + l * HID, ln2g + l * HID, ln2b + l * HID, act16);

    // ---- feedforward ----
    mfma_gemm<128, 1, 1, 0><<<dim3(FF / 128, NTOK / 128, 1), 256, 0, stream>>>(
        act16, wt1, b1 + l * FF, nullptr, ff16, NTOK, HID, FF, HID);
    mfma_gemm<64, 0, 0, 1><<<dim3(HID / 64, NTOK / 128, 2), 256, 0, stream>>>(
        ff16, wt2, nullptr, nullptr, skbuf, NTOK, FF, HID, FF / 2);
    if (l < L - 1) {
      combine_ln<0><<<NTOK, 256, 0, stream>>>(
          skbuf, x, b2 + l * HID, ln1g + (l + 1) * HID, ln1b + (l + 1) * HID,
          act16);
    } else {
      combine_ln<1><<<NTOK, 256, 0, stream>>>(
          skbuf, x, b2 + l * HID, lnfg, lnfb, out);
    }
  }
}

// Round 14
// 4300.823 us; speedup vs baseline: 1.0017x; 1.0007x over previous
//
#include <hip/hip_runtime.h>
#include <hip/hip_bf16.h>
#include <cstddef>
#include <cstdint>

// ---------------------------------------------------------------------------
// DeBERTa forward, MI355X. Round 11: r10 + (a) T14 reg-prefetch of the QP/KP
// HBM streams in flash_attn (K/V stay sync; 4 blocks/CU kept), (b) O-proj
// split-K x2 with combine_ln-fused bias+residual+LN2 (ln2 dispatch deleted).
// B=8 S=512 HID=768 L=12 NH=12 D=64 FF=3072 2M=1024
// ---------------------------------------------------------------------------

constexpr int B   = 8;
constexpr int S   = 512;
constexpr int HID = 768;
constexpr int L   = 12;
constexpr int NH  = 12;
constexpr int D   = 64;
constexpr int FF  = 3072;
constexpr int M2  = 1024;          // 2*M
constexpr int NTOK = B * S;        // 4096

using f32x4 = __attribute__((ext_vector_type(4))) float;
using s16x8 = __attribute__((ext_vector_type(8))) short;
typedef unsigned short us;

__device__ inline float wave_sum(float v) {
#pragma unroll
  for (int o = 32; o > 0; o >>= 1) v += __shfl_xor(v, o, 64);
  return v;
}
__device__ inline us f2bf(float f) {
  __hip_bfloat16 h = __float2bfloat16(f);
  return *reinterpret_cast<us*>(&h);
}
__device__ inline float bf2f(us u) {
  union { unsigned int i; float f; } x;
  x.i = ((unsigned int)u) << 16;
  return x.f;
}
// swizzled elem offset into a [rows][64] bf16 tile (128B rows): granule^row&7
__device__ inline int swz8(int row, int g) {
  return row * 64 + ((g ^ (row & 7)) << 3);
}
// scalar element read index for swizzled tile: element c of row r
__device__ inline int swze(int r, int c) {
  return r * 64 + ((((c >> 3) ^ (r & 7)) << 3) | (c & 7));
}
#define GLOAD16(gp, lp)                                                  \
  __builtin_amdgcn_global_load_lds(                                     \
      (const __attribute__((address_space(1))) void*)(gp),              \
      (__attribute__((address_space(3))) void*)(lp), 16, 0, 0)

// ---- embeddings -------------------------------------------------------------
__global__ void embed_kernel(const int* __restrict__ tok,
                             const int* __restrict__ seg,
                             const float* __restrict__ tok_emb,
                             const float* __restrict__ seg_emb,
                             float* __restrict__ x) {
  int row = blockIdx.x;
  int s = row & (S - 1);
  int t = tok[row];
  int sg = seg[row];
  for (int c = threadIdx.x; c < HID; c += blockDim.x) {
    int i = c >> 1;
    float ang = (float)s * powf(10000.0f, -2.0f * (float)i / (float)HID);
    float pe = (c & 1) ? cosf(ang) : sinf(ang);
    x[(size_t)row * HID + c] = tok_emb[(size_t)t * HID + c] + pe
                             + seg_emb[(size_t)sg * HID + c];
  }
}

// ---- layernorm (one wave per row) -------------------------------------------
template <int BF16OUT>
__global__ __launch_bounds__(256)
void ln_kernel(const float* __restrict__ in, void* __restrict__ outp,
               const float* __restrict__ g, const float* __restrict__ b,
               int nrows) {
  int wave = threadIdx.x >> 6, lane = threadIdx.x & 63;
  int row = blockIdx.x * 4 + wave;
  if (row >= nrows) return;
  const float* xr = in + (size_t)row * HID;
  float v[12];
  float s = 0.f;
#pragma unroll
  for (int i = 0; i < 12; i++) { v[i] = xr[lane + i * 64]; s += v[i]; }
  s = wave_sum(s);
  float mu = s * (1.0f / HID);
  float ss = 0.f;
#pragma unroll
  for (int i = 0; i < 12; i++) { float d = v[i] - mu; ss += d * d; }
  ss = wave_sum(ss);
  float inv = rsqrtf(ss * (1.0f / HID) + 1e-5f);
#pragma unroll
  for (int i = 0; i < 12; i++) {
    int c = lane + i * 64;
    float o = (v[i] - mu) * inv * g[c] + b[c];
    if (BF16OUT)
      ((us*)outp)[(size_t)row * HID + c] = f2bf(o);
    else
      ((float*)outp)[(size_t)row * HID + c] = o;
  }
}

// ---- merged weight prep: 6 square transposes + W1 + W2 + rel conv -----------
__global__ __launch_bounds__(256)
void weight_prep(const float* Wq, const float* Wk, const float* Wv,
                 const float* Wo, const float* Wpk, const float* Wpq,
                 const float* W1s, const float* W2s, const float* rel,
                 us* __restrict__ wt6, us* __restrict__ wt1,
                 us* __restrict__ wt2, us* __restrict__ rel16) {
  int bz = blockIdx.x;
  if (bz >= 8064) {                 // rel f32 -> bf16, 4/thread
    int i = (bz - 8064) * 1024 + threadIdx.x * 4;
    f32x4 v = *(const f32x4*)&rel[i];
#pragma unroll
    for (int j = 0; j < 4; j++) rel16[i + j] = f2bf(v[j]);
    return;
  }
  __shared__ float tile[32][33];
  int tx = threadIdx.x & 31, ty = threadIdx.x >> 5;
  const float* src;
  us* dst;
  int N, K, nt, kt;
  if (bz < 3456) {                  // 6 square [HID,HID]
    int z = bz / 576, r = bz % 576;
    const float* srcs[6] = {Wq, Wk, Wv, Wo, Wpk, Wpq};
    src = srcs[z];
    dst = wt6 + (size_t)z * HID * HID;
    N = HID; K = HID;
    nt = (r % 24) * 32; kt = (r / 24) * 32;
  } else if (bz < 5760) {           // W1 [768,3072] -> [3072,768]
    int r = bz - 3456;
    src = W1s; dst = wt1; N = FF; K = HID;
    nt = (r % 96) * 32; kt = (r / 96) * 32;
  } else {                          // W2 [3072,768] -> [768,3072]
    int r = bz - 5760;
    src = W2s; dst = wt2; N = HID; K = FF;
    nt = (r % 24) * 32; kt = (r / 24) * 32;
  }
#pragma unroll
  for (int i = 0; i < 4; i++)
    tile[ty + i * 8][tx] = src[(size_t)(kt + ty + i * 8) * N + nt + tx];
  __syncthreads();
#pragma unroll
  for (int i = 0; i < 4; i++)
    dst[(size_t)(nt + ty + i * 8) * K + kt + tx] = f2bf(tile[tx][ty + i * 8]);
}

__global__ void concat_bias(const float* __restrict__ bq,
                            const float* __restrict__ bk,
                            const float* __restrict__ bv,
                            float* __restrict__ bqkv) {
  int i = blockIdx.x * 256 + threadIdx.x;
  if (i >= L * 2304) return;
  int l = i / 2304, c = i % 2304;
  float v = (c < 768) ? bq[l * 768 + c]
          : (c < 1536) ? bk[l * 768 + c - 768] : bv[l * 768 + c - 1536];
  bqkv[i] = v;
}

// ---- bf16 MFMA GEMM, 128xTN tile, optional split-K partial ------------------
template <int TN, int OUT_BF16, int GELU, int PARTIAL>
__global__ __launch_bounds__(256)
void mfma_gemm(const us* __restrict__ A, const us* __restrict__ Bt,
               const float* __restrict__ bias, const float* __restrict__ res,
               void* __restrict__ C, int Mr, int K, int N, int Kc) {
  constexpr int NW = TN / 32;
  __shared__ us As[128 * 32];
  __shared__ us Bs[TN * 32];
  int t = threadIdx.x, wave = t >> 6, lane = t & 63;
  int r0 = blockIdx.y * 128, n0 = blockIdx.x * TN;
  int kb = blockIdx.z * Kc;
  int wr = (wave >> 1) * 64;
  int wc = (wave & 1) * (TN / 2);

  f32x4 acc[4][NW] = {};
  int srow = lane >> 2, selem = (lane & 3) * 8;

  for (int k0 = kb; k0 < kb + Kc; k0 += 32) {
    __syncthreads();
    {
      const us* gA = A + (size_t)(r0 + wave * 32 + srow) * K + k0 + selem;
      us* lA = &As[(wave * 32) * 32];
      GLOAD16(gA, lA);
      GLOAD16(gA + (size_t)16 * K, lA + 16 * 32);
      if (TN == 128) {
        const us* gB = Bt + (size_t)(n0 + wave * 32 + srow) * K + k0 + selem;
        us* lB = &Bs[(wave * 32) * 32];
        GLOAD16(gB, lB);
        GLOAD16(gB + (size_t)16 * K, lB + 16 * 32);
      } else {
        const us* gB = Bt + (size_t)(n0 + wave * 16 + srow) * K + k0 + selem;
        GLOAD16(gB, &Bs[(wave * 16) * 32]);
      }
    }
    __syncthreads();

    s16x8 af[4], bf[NW];
#pragma unroll
    for (int m = 0; m < 4; m++)
      af[m] = *(const s16x8*)&As[(wr + m * 16 + (lane & 15)) * 32 + (lane >> 4) * 8];
#pragma unroll
    for (int n = 0; n < NW; n++)
      bf[n] = *(const s16x8*)&Bs[(wc + n * 16 + (lane & 15)) * 32 + (lane >> 4) * 8];
#pragma unroll
    for (int m = 0; m < 4; m++)
#pragma unroll
      for (int n = 0; n < NW; n++)
        acc[m][n] = __builtin_amdgcn_mfma_f32_16x16x32_bf16(af[m], bf[n],
                                                            acc[m][n], 0, 0, 0);
  }

  if (PARTIAL) {
    float* Cp = (float*)C + (size_t)blockIdx.z * Mr * N;
#pragma unroll
    for (int n = 0; n < NW; n++) {
      int c = n0 + wc + n * 16 + (lane & 15);
#pragma unroll
      for (int m = 0; m < 4; m++) {
        int rb = r0 + wr + m * 16 + ((lane >> 4) << 2);
#pragma unroll
        for (int j = 0; j < 4; j++)
          Cp[(size_t)(rb + j) * N + c] = acc[m][n][j];
      }
    }
    return;
  }
#pragma unroll
  for (int n = 0; n < NW; n++) {
    int c = n0 + wc + n * 16 + (lane & 15);
    float bv = bias ? bias[c] : 0.f;
#pragma unroll
    for (int m = 0; m < 4; m++) {
      int rb = r0 + wr + m * 16 + ((lane >> 4) << 2);
#pragma unroll
      for (int j = 0; j < 4; j++) {
        int r = rb + j;
        float val = acc[m][n][j] + bv;
        if (GELU) val = 0.5f * val * (1.0f + erff(val * 0.70710678118654752f));
        if (res)  val += res[(size_t)r * N + c];
        if (OUT_BF16)
          ((us*)C)[(size_t)r * N + c] = f2bf(val);
        else
          ((float*)C)[(size_t)r * N + c] = val;
      }
    }
  }
}

// ---- split-K combine + residual + LN ----------------------------------------
template <int LAST>
__global__ __launch_bounds__(256)
void combine_ln(const float* __restrict__ part,   // [2][NTOK][HID]
                float* __restrict__ x, const float* __restrict__ bias,
                const float* __restrict__ g, const float* __restrict__ bb,
                void* __restrict__ outp) {
  int row = blockIdx.x, t = threadIdx.x;
  int wave = t >> 6, lane = t & 63;
  __shared__ float red[4];
  float v[3];
  float s = 0.f;
#pragma unroll
  for (int i = 0; i < 3; i++) {
    int c = t + i * 256;
    size_t idx = (size_t)row * HID + c;
    float val = x[idx] + part[idx] + part[(size_t)NTOK * HID + idx] + bias[c];
    if (!LAST) x[idx] = val;
    v[i] = val;
    s += val;
  }
  s = wave_sum(s);
  if (lane == 0) red[wave] = s;
  __syncthreads();
  float mu = (red[0] + red[1] + red[2] + red[3]) * (1.0f / HID);
  float ss = 0.f;
#pragma unroll
  for (int i = 0; i < 3; i++) { float d = v[i] - mu; ss += d * d; }
  ss = wave_sum(ss);
  __syncthreads();
  if (lane == 0) red[wave] = ss;
  __syncthreads();
  float inv = rsqrtf((red[0] + red[1] + red[2] + red[3]) * (1.0f / HID) + 1e-5f);
#pragma unroll
  for (int i = 0; i < 3; i++) {
    int c = t + i * 256;
    float o = (v[i] - mu) * inv * g[c] + bb[c];
    if (LAST)
      ((float*)outp)[(size_t)row * HID + c] = o;
    else
      ((us*)outp)[(size_t)row * HID + c] = f2bf(o);
  }
}

// ---- V transpose from fused qkv ----------------------------------------------
__global__ __launch_bounds__(256)
void transpose_v(const us* __restrict__ qkv, us* __restrict__ vt) {
  __shared__ us tile[32][34];
  int bh = blockIdx.z;
  int b = bh / NH, h = bh % NH;
  int s0 = blockIdx.x * 32, d0 = blockIdx.y * 32;
  int tx = threadIdx.x & 31, ty = threadIdx.x >> 5;
#pragma unroll
  for (int i = 0; i < 4; i++)
    tile[ty + i * 8][tx] =
        qkv[(size_t)(b * S + s0 + ty + i * 8) * 2304 + 1536 + h * 64 + d0 + tx];
  __syncthreads();
#pragma unroll
  for (int i = 0; i < 4; i++)
    vt[((size_t)bh * 64 + d0 + ty + i * 8) * S + s0 + tx] = tile[tx][ty + i * 8];
}

// ---- QP/KP precompute: banded GEMM with shifted store ------------------------
// z=0: QP[q,j] = Q_q . pk[q+1+j]   z=1: KP[k,j] = K_k . pq[k+1+j]
__global__ __launch_bounds__(256)
void qpkp_kernel(const us* __restrict__ qkv, const us* __restrict__ pkq,
                 us* __restrict__ QP, us* __restrict__ KP) {
  __shared__ us As[64 * 64];   // A tile (swz)
  __shared__ us Bs[64 * 64];   // B chunk (swz)
  int t = threadIdx.x, wave = t >> 6, lane = t & 63;
  int l15 = lane & 15, l4 = lane >> 4;
  int t0 = blockIdx.x * 64;
  int bh = blockIdx.y;              // 0..95
  int b = bh / NH, h = bh % NH;
  int z = blockIdx.z;
  int zoff = z * 768;
  us* outp = (z ? KP : QP) + ((size_t)bh * 512 + t0) * 512;

  // stage A (64 rows of Q or K for this head)
#pragma unroll
  for (int i = 0; i < 2; i++) {
    int c = t + i * 256;
    int r = c >> 3, g = c & 7;
    *(s16x8*)&As[swz8(r, g)] =
        *(const s16x8*)&qkv[(size_t)(b * S + t0 + r) * 2304 + zoff + h * 64 + g * 8];
  }

  s16x8 af[2];
  for (int c = 0; c < 9; c++) {
    // stage B chunk: pk/pq rows t0+1+c*64 .. +63 (clamped; clamped rows unused)
#pragma unroll
    for (int i = 0; i < 2; i++) {
      int cc = t + i * 256;
      int rr = cc >> 3, g = cc & 7;
      int rb = t0 + 1 + c * 64 + rr;
      rb = rb > M2 - 1 ? M2 - 1 : rb;
      *(s16x8*)&Bs[swz8(rr, g)] =
          *(const s16x8*)&pkq[(size_t)rb * 1536 + zoff + h * 64 + g * 8];
    }
    __syncthreads();
    if (c == 0) {
#pragma unroll
      for (int ks = 0; ks < 2; ks++)
        af[ks] = *(const s16x8*)&As[swz8(wave * 16 + l15, ks * 4 + l4)];
    }
    f32x4 acc[4] = {};
#pragma unroll
    for (int ks = 0; ks < 2; ks++)
#pragma unroll
      for (int n = 0; n < 4; n++) {
        s16x8 bf = *(const s16x8*)&Bs[swz8(n * 16 + l15, ks * 4 + l4)];
        acc[n] = __builtin_amdgcn_mfma_f32_16x16x32_bf16(af[ks], bf, acc[n], 0, 0, 0);
      }
    // shifted store: out[row=iq][j=rc'-iq] for 0<=j<512
#pragma unroll
    for (int n = 0; n < 4; n++) {
      int rcp = c * 64 + n * 16 + l15;
#pragma unroll
      for (int jj = 0; jj < 4; jj++) {
        int iq = wave * 16 + (l4 << 2) + jj;
        int j = rcp - iq;
        if ((unsigned)j < 512u)
          outp[(size_t)iq * 512 + j] = f2bf(acc[n][jj]);
      }
    }
    __syncthreads();
  }
}

// ---- flash attention v6: table scores + T14 reg-prefetch of QP/KP streams ----
// scores[q,k] = (c2c + QP[q,511-k] + KP[k,511-q]) * scale, masked.
// QP/KP (read-once HBM streams) prefetched into regs one tile ahead; K/V
// (L2-resident) staged synchronously at tile tail. 40KB LDS -> 4 blocks/CU.
__global__ __launch_bounds__(256, 4)
void flash_attn(const us* __restrict__ qkv,
                const us* __restrict__ QP,    // [96*512][512]
                const us* __restrict__ KP,
                const us* __restrict__ vt,    // [B*NH*64][S]
                const int* __restrict__ tok,
                us* __restrict__ ctx) {
  __shared__ us Ks[4096];    // K tile (swz)
  __shared__ us Vs[4096];    // V^T tile (swz)
  __shared__ us QPs[4096];   // QP slab tile (swz)
  __shared__ us KPs[4096];   // KP slab tile (swz)
  __shared__ us Ps[4096];    // P (swz)

  int t = threadIdx.x, wave = t >> 6, lane = t & 63;
  int bh = blockIdx.y;
  int b = bh / NH, h = bh % NH;
  int q0 = blockIdx.x * 64;
  int l15 = lane & 15, l4 = lane >> 4;
  const float scale = 0.07216878364870323f;   // 1/sqrt(3*64)

  // staging coords for this thread (2 chunks x (row, granule))
  int sr0 = t >> 3, sg0 = t & 7;              // chunk 0: rows 0..31
  int sr1 = sr0 + 32;                         // chunk 1: rows 32..63

  // persistent Q fragments (wave's 16 q-rows)
  s16x8 qf[2];
#pragma unroll
  for (int ks = 0; ks < 2; ks++)
    qf[ks] = *(const s16x8*)&qkv[(size_t)(b * S + q0 + wave * 16 + l15) * 2304
                                 + h * 64 + ks * 32 + l4 * 8];

  // ---- prologue: stage all 4 tiles for k0 = 0 ----
  {
    *(s16x8*)&Ks[swz8(sr0, sg0)] =
        *(const s16x8*)&qkv[(size_t)(b * S + sr0) * 2304 + 768 + h * 64 + sg0 * 8];
    *(s16x8*)&Ks[swz8(sr1, sg0)] =
        *(const s16x8*)&qkv[(size_t)(b * S + sr1) * 2304 + 768 + h * 64 + sg0 * 8];
    *(s16x8*)&Vs[swz8(sr0, sg0)] =
        *(const s16x8*)&vt[((size_t)bh * 64 + sr0) * S + sg0 * 8];
    *(s16x8*)&Vs[swz8(sr1, sg0)] =
        *(const s16x8*)&vt[((size_t)bh * 64 + sr1) * S + sg0 * 8];
    *(s16x8*)&QPs[swz8(sr0, sg0)] =
        *(const s16x8*)&QP[((size_t)bh * 512 + q0 + sr0) * 512 + 448 + sg0 * 8];
    *(s16x8*)&QPs[swz8(sr1, sg0)] =
        *(const s16x8*)&QP[((size_t)bh * 512 + q0 + sr1) * 512 + 448 + sg0 * 8];
    *(s16x8*)&KPs[swz8(sr0, sg0)] =
        *(const s16x8*)&KP[((size_t)bh * 512 + sr0) * 512 + (448 - q0) + sg0 * 8];
    *(s16x8*)&KPs[swz8(sr1, sg0)] =
        *(const s16x8*)&KP[((size_t)bh * 512 + sr1) * 512 + (448 - q0) + sg0 * 8];
  }
  __syncthreads();                                    // tile 0 visible

  float m[4], l[4];
  f32x4 accO[4];
#pragma unroll
  for (int j = 0; j < 4; j++) { m[j] = -1e30f; l[j] = 0.f; }
#pragma unroll
  for (int n = 0; n < 4; n++) accO[n] = (f32x4){0.f, 0.f, 0.f, 0.f};

  for (int k0 = 0; k0 < S; k0 += 64) {
    int k0n = k0 + 64;
    bool pf = (k0n < S);

    // ---- T14: issue next tile's QP/KP stream loads into regs ----
    s16x8 pfQ0, pfQ1, pfK0, pfK1;
    if (pf) {
      pfQ0 = *(const s16x8*)&QP[((size_t)bh * 512 + q0 + sr0) * 512 + (448 - k0n) + sg0 * 8];
      pfQ1 = *(const s16x8*)&QP[((size_t)bh * 512 + q0 + sr1) * 512 + (448 - k0n) + sg0 * 8];
      pfK0 = *(const s16x8*)&KP[((size_t)bh * 512 + k0n + sr0) * 512 + (448 - q0) + sg0 * 8];
      pfK1 = *(const s16x8*)&KP[((size_t)bh * 512 + k0n + sr1) * 512 + (448 - q0) + sg0 * 8];
    }

    // ---- c2c MFMAs ----
    f32x4 c2c[4] = {};
#pragma unroll
    for (int ks = 0; ks < 2; ks++) {
      int g = ks * 4 + l4;
#pragma unroll
      for (int n = 0; n < 4; n++) {
        s16x8 bk = *(const s16x8*)&Ks[swz8(n * 16 + l15, g)];
        c2c[n] = __builtin_amdgcn_mfma_f32_16x16x32_bf16(qf[ks], bk, c2c[n], 0, 0, 0);
      }
    }

    // ---- score assembly + online softmax ----
    float p[4][4];
    float rmax[4];
#pragma unroll
    for (int j = 0; j < 4; j++) rmax[j] = -1e30f;
#pragma unroll
    for (int n = 0; n < 4; n++) {
      int ik = n * 16 + l15;
      bool msk = (tok[b * S + k0 + ik] == 0);
      int ccp = 63 - ik;             // QPs col for this k
#pragma unroll
      for (int j = 0; j < 4; j++) {
        int iq = wave * 16 + (l4 << 2) + j;
        float sc = c2c[n][j]
                 + bf2f(QPs[swze(iq, ccp)])
                 + bf2f(KPs[swze(ik, 63 - iq)]);
        sc *= scale;
        if (msk) sc = -1e9f;
        p[n][j] = sc;
        rmax[j] = fmaxf(rmax[j], sc);
      }
    }
#pragma unroll
    for (int o = 8; o > 0; o >>= 1)
#pragma unroll
      for (int j = 0; j < 4; j++)
        rmax[j] = fmaxf(rmax[j], __shfl_xor(rmax[j], o, 64));
    float al[4];
#pragma unroll
    for (int j = 0; j < 4; j++) {
      float mn = fmaxf(m[j], rmax[j]);
      al[j] = __expf(m[j] - mn);
      m[j] = mn;
    }
    float rs[4] = {0.f, 0.f, 0.f, 0.f};
#pragma unroll
    for (int n = 0; n < 4; n++)
#pragma unroll
      for (int j = 0; j < 4; j++) {
        p[n][j] = __expf(p[n][j] - m[j]);
        rs[j] += p[n][j];
      }
#pragma unroll
    for (int o = 8; o > 0; o >>= 1)
#pragma unroll
      for (int j = 0; j < 4; j++) rs[j] += __shfl_xor(rs[j], o, 64);
#pragma unroll
    for (int j = 0; j < 4; j++) l[j] = l[j] * al[j] + rs[j];
#pragma unroll
    for (int n = 0; n < 4; n++)
#pragma unroll
      for (int j = 0; j < 4; j++) accO[n][j] *= al[j];

    // ---- P -> Ps ----
    {
      int rw = wave * 16 + (l4 << 2);
#pragma unroll
      for (int n = 0; n < 4; n++)
#pragma unroll
        for (int j = 0; j < 4; j++)
          Ps[swze(rw + j, n * 16 + l15)] = f2bf(p[n][j]);
    }
    __syncthreads();                                  // (2) P visible

    // ---- PV: accO += P @ V ----
#pragma unroll
    for (int ks = 0; ks < 2; ks++) {
      int g = ks * 4 + l4;
      s16x8 ap = *(const s16x8*)&Ps[swz8(wave * 16 + l15, g)];
#pragma unroll
      for (int n = 0; n < 4; n++) {
        s16x8 bv2 = *(const s16x8*)&Vs[swz8(n * 16 + l15, g)];
        accO[n] = __builtin_amdgcn_mfma_f32_16x16x32_bf16(ap, bv2, accO[n], 0, 0, 0);
      }
    }
    __syncthreads();                                  // (3) all reads done

    // ---- tail staging for k0n: prefetched QP/KP + sync K/V (L2-hot) ----
    if (pf) {
      *(s16x8*)&QPs[swz8(sr0, sg0)] = pfQ0;
      *(s16x8*)&QPs[swz8(sr1, sg0)] = pfQ1;
      *(s16x8*)&KPs[swz8(sr0, sg0)] = pfK0;
      *(s16x8*)&KPs[swz8(sr1, sg0)] = pfK1;
      *(s16x8*)&Ks[swz8(sr0, sg0)] =
          *(const s16x8*)&qkv[(size_t)(b * S + k0n + sr0) * 2304 + 768 + h * 64 + sg0 * 8];
      *(s16x8*)&Ks[swz8(sr1, sg0)] =
          *(const s16x8*)&qkv[(size_t)(b * S + k0n + sr1) * 2304 + 768 + h * 64 + sg0 * 8];
      *(s16x8*)&Vs[swz8(sr0, sg0)] =
          *(const s16x8*)&vt[((size_t)bh * 64 + sr0) * S + k0n + sg0 * 8];
      *(s16x8*)&Vs[swz8(sr1, sg0)] =
          *(const s16x8*)&vt[((size_t)bh * 64 + sr1) * S + k0n + sg0 * 8];
      __syncthreads();                                // (1) next tile visible
    }
  }

  // ---- epilogue: O = accO / l ----
#pragma unroll
  for (int n = 0; n < 4; n++) {
    int dd = h * 64 + n * 16 + l15;
#pragma unroll
    for (int j = 0; j < 4; j++) {
      int iq = q0 + wave * 16 + (l4 << 2) + j;
      ctx[(size_t)(b * S + iq) * HID + dd] = f2bf(accO[n][j] / l[j]);
    }
  }
}

// ---------------------------------------------------------------------------
extern "C" void kernel_launch(void* const* d_in, const int* in_sizes, int n_in,
                              void* d_out, int out_size, void* d_ws,
                              size_t ws_size, hipStream_t stream) {
  (void)in_sizes; (void)n_in; (void)out_size; (void)ws_size;
  const int*   tok     = (const int*)d_in[0];
  const int*   seg     = (const int*)d_in[1];
  const float* tok_emb = (const float*)d_in[2];
  const float* seg_emb = (const float*)d_in[3];
  const float* Wq  = (const float*)d_in[4];
  const float* bq  = (const float*)d_in[5];
  const float* Wk  = (const float*)d_in[6];
  const float* bk  = (const float*)d_in[7];
  const float* Wv  = (const float*)d_in[8];
  const float* bv  = (const float*)d_in[9];
  const float* Wo  = (const float*)d_in[10];
  const float* bo  = (const float*)d_in[11];
  const float* Wpk = (const float*)d_in[12];
  const float* Wpq = (const float*)d_in[13];
  const float* rel = (const float*)d_in[14];
  const float* ln1g = (const float*)d_in[15];
  const float* ln1b = (const float*)d_in[16];
  const float* ln2g = (const float*)d_in[17];
  const float* ln2b = (const float*)d_in[18];
  const float* W1  = (const float*)d_in[19];
  const float* b1  = (const float*)d_in[20];
  const float* W2  = (const float*)d_in[21];
  const float* b2  = (const float*)d_in[22];
  const float* lnfg = (const float*)d_in[23];
  const float* lnfb = (const float*)d_in[24];
  float* out = (float*)d_out;

  // ---- workspace layout (~281 MB of ~528 MB) ----
  char* base = (char*)d_ws;
  size_t off = 0;
  auto alloc = [&](size_t bytes) -> void* {
    void* p = base + off;
    off += (bytes + 255) & ~(size_t)255;
    return p;
  };
  const size_t XSZ = (size_t)NTOK * HID;
  float* x = (float*)alloc(XSZ * 4);
  us* qkv16 = (us*)alloc((size_t)NTOK * 2304 * 2);
  us* pkq16 = (us*)alloc((size_t)M2 * 1536 * 2);
  us* vt16  = (us*)alloc(XSZ * 2);
  us* act16 = (us*)alloc(XSZ * 2);
  us* ff16  = (us*)alloc((size_t)NTOK * FF * 2);
  us* rel16 = (us*)alloc((size_t)M2 * HID * 2);
  us* wt6   = (us*)alloc((size_t)6 * HID * HID * 2);
  us* wt1   = (us*)alloc((size_t)HID * FF * 2);
  us* wt2   = (us*)alloc((size_t)HID * FF * 2);
  float* skbuf = (float*)alloc((size_t)2 * NTOK * HID * 4);
  float* bqkv  = (float*)alloc((size_t)L * 2304 * 4);
  us* QP = (us*)alloc((size_t)B * NH * S * 512 * 2);   // 50.33 MB
  us* KP = (us*)alloc((size_t)B * NH * S * 512 * 2);   // 50.33 MB

  const size_t WSQ = (size_t)HID * HID;

  embed_kernel<<<NTOK, 256, 0, stream>>>(tok, seg, tok_emb, seg_emb, x);
  concat_bias<<<(L * 2304 + 255) / 256, 256, 0, stream>>>(bq, bk, bv, bqkv);
  ln_kernel<1><<<NTOK / 4, 256, 0, stream>>>(x, act16, ln1g, ln1b, NTOK);

  for (int l = 0; l < L; l++) {
    // ---- merged weight prep (slots: 0=q 1=k 2=v 3=o 4=pk 5=pq) ----
    weight_prep<<<8832, 256, 0, stream>>>(
        Wq + l * WSQ, Wk + l * WSQ, Wv + l * WSQ, Wo + l * WSQ,
        Wpk + l * WSQ, Wpq + l * WSQ, W1 + (size_t)l * HID * FF,
        W2 + (size_t)l * FF * HID, rel + (size_t)l * M2 * HID,
        wt6, wt1, wt2, rel16);

    // ---- attention ----
    mfma_gemm<128, 1, 0, 0><<<dim3(2304 / 128, NTOK / 128, 1), 256, 0, stream>>>(
        act16, wt6, bqkv + l * 2304, nullptr, qkv16, NTOK, HID, 2304, HID);
    mfma_gemm<64, 1, 0, 0><<<dim3(1536 / 64, M2 / 128, 1), 256, 0, stream>>>(
        rel16, wt6 + 4 * WSQ, nullptr, nullptr, pkq16, M2, HID, 1536, HID);
    transpose_v<<<dim3(S / 32, D / 32, B * NH), 256, 0, stream>>>(qkv16, vt16);
    qpkp_kernel<<<dim3(S / 64, B * NH, 2), 256, 0, stream>>>(
        qkv16, pkq16, QP, KP);
    flash_attn<<<dim3(S / 64, B * NH), 256, 0, stream>>>(
        qkv16, QP, KP, vt16, tok, act16);

    // ---- O-proj: split-K x2 partials + fused (bias + residual + LN2) ----
    mfma_gemm<64, 0, 0, 1><<<dim3(HID / 64, NTOK / 128, 2), 256, 0, stream>>>(
        act16, wt6 + 3 * WSQ, nullptr, nullptr, skbuf, NTOK, HID, HID, HID / 2);
    combine_ln<0><<<NTOK, 256, 0, stream>>>(
        skbuf, x, bo + l * HID, ln2g + l * HID, ln2b + l * HID, act16);

    // ---- feedforward ----
    mfma_gemm<128, 1, 1, 0><<<dim3(FF / 128, NTOK / 128, 1), 256, 0, stream>>>(
        act16, wt1, b1 + l * FF, nullptr, ff16, NTOK, HID, FF, HID);
    mfma_gemm<64, 0, 0, 1><<<dim3(HID / 64, NTOK / 128, 2), 256, 0, stream>>>(
        ff16, wt2, nullptr, nullptr, skbuf, NTOK, FF, HID, FF / 2);
    if (l < L - 1) {
      combine_ln<0><<<NTOK, 256, 0, stream>>>(
          skbuf, x, b2 + l * HID, ln1g + (l + 1) * HID, ln1b + (l + 1) * HID,
          act16);
    } else {
      combine_ln<1><<<NTOK, 256, 0, stream>>>(
          skbuf, x, b2 + l * HID, lnfg, lnfb, out);
    }
  }
}

// Round 15
// 4289.870 us; speedup vs baseline: 1.0043x; 1.0026x over previous
//
#include <hip/hip_runtime.h>
#include <hip/hip_bf16.h>
#include <cstddef>
#include <cstdint>

// ---------------------------------------------------------------------------
// DeBERTa forward, MI355X. Round 11: r10 + (a) T14 reg-prefetch of the QP/KP
// HBM streams in flash_attn (K/V stay sync; 4 blocks/CU kept), (b) O-proj
// split-K x2 with combine_ln-fused bias+residual+LN2 (ln2 dispatch deleted).
// B=8 S=512 HID=768 L=12 NH=12 D=64 FF=3072 2M=1024
// ---------------------------------------------------------------------------

constexpr int B   = 8;
constexpr int S   = 512;
constexpr int HID = 768;
constexpr int L   = 12;
constexpr int NH  = 12;
constexpr int D   = 64;
constexpr int FF  = 3072;
constexpr int M2  = 1024;          // 2*M
constexpr int NTOK = B * S;        // 4096

using f32x4 = __attribute__((ext_vector_type(4))) float;
using s16x8 = __attribute__((ext_vector_type(8))) short;
typedef unsigned short us;

__device__ inline float wave_sum(float v) {
#pragma unroll
  for (int o = 32; o > 0; o >>= 1) v += __shfl_xor(v, o, 64);
  return v;
}
__device__ inline us f2bf(float f) {
  __hip_bfloat16 h = __float2bfloat16(f);
  return *reinterpret_cast<us*>(&h);
}
__device__ inline float bf2f(us u) {
  union { unsigned int i; float f; } x;
  x.i = ((unsigned int)u) << 16;
  return x.f;
}
// swizzled elem offset into a [rows][64] bf16 tile (128B rows): granule^row&7
__device__ inline int swz8(int row, int g) {
  return row * 64 + ((g ^ (row & 7)) << 3);
}
// scalar element read index for swizzled tile: element c of row r
__device__ inline int swze(int r, int c) {
  return r * 64 + ((((c >> 3) ^ (r & 7)) << 3) | (c & 7));
}
#define GLOAD16(gp, lp)                                                  \
  __builtin_amdgcn_global_load_lds(                                     \
      (const __attribute__((address_space(1))) void*)(gp),              \
      (__attribute__((address_space(3))) void*)(lp), 16, 0, 0)

// ---- embeddings -------------------------------------------------------------
__global__ void embed_kernel(const int* __restrict__ tok,
                             const int* __restrict__ seg,
                             const float* __restrict__ tok_emb,
                             const float* __restrict__ seg_emb,
                             float* __restrict__ x) {
  int row = blockIdx.x;
  int s = row & (S - 1);
  int t = tok[row];
  int sg = seg[row];
  for (int c = threadIdx.x; c < HID; c += blockDim.x) {
    int i = c >> 1;
    float ang = (float)s * powf(10000.0f, -2.0f * (float)i / (float)HID);
    float pe = (c & 1) ? cosf(ang) : sinf(ang);
    x[(size_t)row * HID + c] = tok_emb[(size_t)t * HID + c] + pe
                             + seg_emb[(size_t)sg * HID + c];
  }
}

// ---- layernorm (one wave per row) -------------------------------------------
template <int BF16OUT>
__global__ __launch_bounds__(256)
void ln_kernel(const float* __restrict__ in, void* __restrict__ outp,
               const float* __restrict__ g, const float* __restrict__ b,
               int nrows) {
  int wave = threadIdx.x >> 6, lane = threadIdx.x & 63;
  int row = blockIdx.x * 4 + wave;
  if (row >= nrows) return;
  const float* xr = in + (size_t)row * HID;
  float v[12];
  float s = 0.f;
#pragma unroll
  for (int i = 0; i < 12; i++) { v[i] = xr[lane + i * 64]; s += v[i]; }
  s = wave_sum(s);
  float mu = s * (1.0f / HID);
  float ss = 0.f;
#pragma unroll
  for (int i = 0; i < 12; i++) { float d = v[i] - mu; ss += d * d; }
  ss = wave_sum(ss);
  float inv = rsqrtf(ss * (1.0f / HID) + 1e-5f);
#pragma unroll
  for (int i = 0; i < 12; i++) {
    int c = lane + i * 64;
    float o = (v[i] - mu) * inv * g[c] + b[c];
    if (BF16OUT)
      ((us*)outp)[(size_t)row * HID + c] = f2bf(o);
    else
      ((float*)outp)[(size_t)row * HID + c] = o;
  }
}

// ---- merged weight prep: 6 square transposes + W1 + W2 + rel conv -----------
__global__ __launch_bounds__(256)
void weight_prep(const float* Wq, const float* Wk, const float* Wv,
                 const float* Wo, const float* Wpk, const float* Wpq,
                 const float* W1s, const float* W2s, const float* rel,
                 us* __restrict__ wt6, us* __restrict__ wt1,
                 us* __restrict__ wt2, us* __restrict__ rel16) {
  int bz = blockIdx.x;
  if (bz >= 8064) {                 // rel f32 -> bf16, 4/thread
    int i = (bz - 8064) * 1024 + threadIdx.x * 4;
    f32x4 v = *(const f32x4*)&rel[i];
#pragma unroll
    for (int j = 0; j < 4; j++) rel16[i + j] = f2bf(v[j]);
    return;
  }
  __shared__ float tile[32][33];
  int tx = threadIdx.x & 31, ty = threadIdx.x >> 5;
  const float* src;
  us* dst;
  int N, K, nt, kt;
  if (bz < 3456) {                  // 6 square [HID,HID]
    int z = bz / 576, r = bz % 576;
    const float* srcs[6] = {Wq, Wk, Wv, Wo, Wpk, Wpq};
    src = srcs[z];
    dst = wt6 + (size_t)z * HID * HID;
    N = HID; K = HID;
    nt = (r % 24) * 32; kt = (r / 24) * 32;
  } else if (bz < 5760) {           // W1 [768,3072] -> [3072,768]
    int r = bz - 3456;
    src = W1s; dst = wt1; N = FF; K = HID;
    nt = (r % 96) * 32; kt = (r / 96) * 32;
  } else {                          // W2 [3072,768] -> [768,3072]
    int r = bz - 5760;
    src = W2s; dst = wt2; N = HID; K = FF;
    nt = (r % 24) * 32; kt = (r / 24) * 32;
  }
#pragma unroll
  for (int i = 0; i < 4; i++)
    tile[ty + i * 8][tx] = src[(size_t)(kt + ty + i * 8) * N + nt + tx];
  __syncthreads();
#pragma unroll
  for (int i = 0; i < 4; i++)
    dst[(size_t)(nt + ty + i * 8) * K + kt + tx] = f2bf(tile[tx][ty + i * 8]);
}

__global__ void concat_bias(const float* __restrict__ bq,
                            const float* __restrict__ bk,
                            const float* __restrict__ bv,
                            float* __restrict__ bqkv) {
  int i = blockIdx.x * 256 + threadIdx.x;
  if (i >= L * 2304) return;
  int l = i / 2304, c = i % 2304;
  float v = (c < 768) ? bq[l * 768 + c]
          : (c < 1536) ? bk[l * 768 + c - 768] : bv[l * 768 + c - 1536];
  bqkv[i] = v;
}

// ---- bf16 MFMA GEMM, 128xTN tile, optional split-K partial ------------------
template <int TN, int OUT_BF16, int GELU, int PARTIAL>
__global__ __launch_bounds__(256)
void mfma_gemm(const us* __restrict__ A, const us* __restrict__ Bt,
               const float* __restrict__ bias, const float* __restrict__ res,
               void* __restrict__ C, int Mr, int K, int N, int Kc) {
  constexpr int NW = TN / 32;
  __shared__ us As[128 * 32];
  __shared__ us Bs[TN * 32];
  int t = threadIdx.x, wave = t >> 6, lane = t & 63;
  int r0 = blockIdx.y * 128, n0 = blockIdx.x * TN;
  int kb = blockIdx.z * Kc;
  int wr = (wave >> 1) * 64;
  int wc = (wave & 1) * (TN / 2);

  f32x4 acc[4][NW] = {};
  int srow = lane >> 2, selem = (lane & 3) * 8;

  for (int k0 = kb; k0 < kb + Kc; k0 += 32) {
    __syncthreads();
    {
      const us* gA = A + (size_t)(r0 + wave * 32 + srow) * K + k0 + selem;
      us* lA = &As[(wave * 32) * 32];
      GLOAD16(gA, lA);
      GLOAD16(gA + (size_t)16 * K, lA + 16 * 32);
      if (TN == 128) {
        const us* gB = Bt + (size_t)(n0 + wave * 32 + srow) * K + k0 + selem;
        us* lB = &Bs[(wave * 32) * 32];
        GLOAD16(gB, lB);
        GLOAD16(gB + (size_t)16 * K, lB + 16 * 32);
      } else {
        const us* gB = Bt + (size_t)(n0 + wave * 16 + srow) * K + k0 + selem;
        GLOAD16(gB, &Bs[(wave * 16) * 32]);
      }
    }
    __syncthreads();

    s16x8 af[4], bf[NW];
#pragma unroll
    for (int m = 0; m < 4; m++)
      af[m] = *(const s16x8*)&As[(wr + m * 16 + (lane & 15)) * 32 + (lane >> 4) * 8];
#pragma unroll
    for (int n = 0; n < NW; n++)
      bf[n] = *(const s16x8*)&Bs[(wc + n * 16 + (lane & 15)) * 32 + (lane >> 4) * 8];
#pragma unroll
    for (int m = 0; m < 4; m++)
#pragma unroll
      for (int n = 0; n < NW; n++)
        acc[m][n] = __builtin_amdgcn_mfma_f32_16x16x32_bf16(af[m], bf[n],
                                                            acc[m][n], 0, 0, 0);
  }

  if (PARTIAL) {
    float* Cp = (float*)C + (size_t)blockIdx.z * Mr * N;
#pragma unroll
    for (int n = 0; n < NW; n++) {
      int c = n0 + wc + n * 16 + (lane & 15);
#pragma unroll
      for (int m = 0; m < 4; m++) {
        int rb = r0 + wr + m * 16 + ((lane >> 4) << 2);
#pragma unroll
        for (int j = 0; j < 4; j++)
          Cp[(size_t)(rb + j) * N + c] = acc[m][n][j];
      }
    }
    return;
  }
#pragma unroll
  for (int n = 0; n < NW; n++) {
    int c = n0 + wc + n * 16 + (lane & 15);
    float bv = bias ? bias[c] : 0.f;
#pragma unroll
    for (int m = 0; m < 4; m++) {
      int rb = r0 + wr + m * 16 + ((lane >> 4) << 2);
#pragma unroll
      for (int j = 0; j < 4; j++) {
        int r = rb + j;
        float val = acc[m][n][j] + bv;
        if (GELU) val = 0.5f * val * (1.0f + erff(val * 0.70710678118654752f));
        if (res)  val += res[(size_t)r * N + c];
        if (OUT_BF16)
          ((us*)C)[(size_t)r * N + c] = f2bf(val);
        else
          ((float*)C)[(size_t)r * N + c] = val;
      }
    }
  }
}

// ---- split-K combine + residual + LN ----------------------------------------
template <int LAST>
__global__ __launch_bounds__(256)
void combine_ln(const float* __restrict__ part,   // [2][NTOK][HID]
                float* __restrict__ x, const float* __restrict__ bias,
                const float* __restrict__ g, const float* __restrict__ bb,
                void* __restrict__ outp) {
  int row = blockIdx.x, t = threadIdx.x;
  int wave = t >> 6, lane = t & 63;
  __shared__ float red[4];
  float v[3];
  float s = 0.f;
#pragma unroll
  for (int i = 0; i < 3; i++) {
    int c = t + i * 256;
    size_t idx = (size_t)row * HID + c;
    float val = x[idx] + part[idx] + part[(size_t)NTOK * HID + idx] + bias[c];
    if (!LAST) x[idx] = val;
    v[i] = val;
    s += val;
  }
  s = wave_sum(s);
  if (lane == 0) red[wave] = s;
  __syncthreads();
  float mu = (red[0] + red[1] + red[2] + red[3]) * (1.0f / HID);
  float ss = 0.f;
#pragma unroll
  for (int i = 0; i < 3; i++) { float d = v[i] - mu; ss += d * d; }
  ss = wave_sum(ss);
  __syncthreads();
  if (lane == 0) red[wave] = ss;
  __syncthreads();
  float inv = rsqrtf((red[0] + red[1] + red[2] + red[3]) * (1.0f / HID) + 1e-5f);
#pragma unroll
  for (int i = 0; i < 3; i++) {
    int c = t + i * 256;
    float o = (v[i] - mu) * inv * g[c] + bb[c];
    if (LAST)
      ((float*)outp)[(size_t)row * HID + c] = o;
    else
      ((us*)outp)[(size_t)row * HID + c] = f2bf(o);
  }
}

// ---- V transpose from fused qkv ----------------------------------------------
__global__ __launch_bounds__(256)
void transpose_v(const us* __restrict__ qkv, us* __restrict__ vt) {
  __shared__ us tile[32][34];
  int bh = blockIdx.z;
  int b = bh / NH, h = bh % NH;
  int s0 = blockIdx.x * 32, d0 = blockIdx.y * 32;
  int tx = threadIdx.x & 31, ty = threadIdx.x >> 5;
#pragma unroll
  for (int i = 0; i < 4; i++)
    tile[ty + i * 8][tx] =
        qkv[(size_t)(b * S + s0 + ty + i * 8) * 2304 + 1536 + h * 64 + d0 + tx];
  __syncthreads();
#pragma unroll
  for (int i = 0; i < 4; i++)
    vt[((size_t)bh * 64 + d0 + ty + i * 8) * S + s0 + tx] = tile[tx][ty + i * 8];
}

// ---- QP/KP precompute: banded GEMM with shifted store ------------------------
// z=0: QP[q,j] = Q_q . pk[q+1+j]   z=1: KP[k,j] = K_k . pq[k+1+j]
__global__ __launch_bounds__(256)
void qpkp_kernel(const us* __restrict__ qkv, const us* __restrict__ pkq,
                 us* __restrict__ QP, us* __restrict__ KP) {
  __shared__ us As[64 * 64];   // A tile (swz)
  __shared__ us Bs[64 * 64];   // B chunk (swz)
  int t = threadIdx.x, wave = t >> 6, lane = t & 63;
  int l15 = lane & 15, l4 = lane >> 4;
  int t0 = blockIdx.x * 64;
  int bh = blockIdx.y;              // 0..95
  int b = bh / NH, h = bh % NH;
  int z = blockIdx.z;
  int zoff = z * 768;
  us* outp = (z ? KP : QP) + ((size_t)bh * 512 + t0) * 512;

  // stage A (64 rows of Q or K for this head)
#pragma unroll
  for (int i = 0; i < 2; i++) {
    int c = t + i * 256;
    int r = c >> 3, g = c & 7;
    *(s16x8*)&As[swz8(r, g)] =
        *(const s16x8*)&qkv[(size_t)(b * S + t0 + r) * 2304 + zoff + h * 64 + g * 8];
  }

  s16x8 af[2];
  for (int c = 0; c < 9; c++) {
    // stage B chunk: pk/pq rows t0+1+c*64 .. +63 (clamped; clamped rows unused)
#pragma unroll
    for (int i = 0; i < 2; i++) {
      int cc = t + i * 256;
      int rr = cc >> 3, g = cc & 7;
      int rb = t0 + 1 + c * 64 + rr;
      rb = rb > M2 - 1 ? M2 - 1 : rb;
      *(s16x8*)&Bs[swz8(rr, g)] =
          *(const s16x8*)&pkq[(size_t)rb * 1536 + zoff + h * 64 + g * 8];
    }
    __syncthreads();
    if (c == 0) {
#pragma unroll
      for (int ks = 0; ks < 2; ks++)
        af[ks] = *(const s16x8*)&As[swz8(wave * 16 + l15, ks * 4 + l4)];
    }
    f32x4 acc[4] = {};
#pragma unroll
    for (int ks = 0; ks < 2; ks++)
#pragma unroll
      for (int n = 0; n < 4; n++) {
        s16x8 bf = *(const s16x8*)&Bs[swz8(n * 16 + l15, ks * 4 + l4)];
        acc[n] = __builtin_amdgcn_mfma_f32_16x16x32_bf16(af[ks], bf, acc[n], 0, 0, 0);
      }
    // shifted store: out[row=iq][j=rc'-iq] for 0<=j<512
#pragma unroll
    for (int n = 0; n < 4; n++) {
      int rcp = c * 64 + n * 16 + l15;
#pragma unroll
      for (int jj = 0; jj < 4; jj++) {
        int iq = wave * 16 + (l4 << 2) + jj;
        int j = rcp - iq;
        if ((unsigned)j < 512u)
          outp[(size_t)iq * 512 + j] = f2bf(acc[n][jj]);
      }
    }
    __syncthreads();
  }
}

// ---- flash attention v6: table scores + T14 reg-prefetch of QP/KP streams ----
// scores[q,k] = (c2c + QP[q,511-k] + KP[k,511-q]) * scale, masked.
// QP/KP (read-once HBM streams) prefetched into regs one tile ahead; K/V
// (L2-resident) staged synchronously at tile tail. 40KB LDS -> 4 blocks/CU.
__global__ __launch_bounds__(256, 4)
void flash_attn(const us* __restrict__ qkv,
                const us* __restrict__ QP,    // [96*512][512]
                const us* __restrict__ KP,
                const us* __restrict__ vt,    // [B*NH*64][S]
                const int* __restrict__ tok,
                us* __restrict__ ctx) {
  __shared__ us Ks[4096];    // K tile (swz)
  __shared__ us Vs[4096];    // V^T tile (swz)
  __shared__ us QPs[4096];   // QP slab tile (swz)
  __shared__ us KPs[4096];   // KP slab tile (swz)
  __shared__ us Ps[4096];    // P (swz)

  int t = threadIdx.x, wave = t >> 6, lane = t & 63;
  int bh = blockIdx.y;
  int b = bh / NH, h = bh % NH;
  int q0 = blockIdx.x * 64;
  int l15 = lane & 15, l4 = lane >> 4;
  const float scale = 0.07216878364870323f;   // 1/sqrt(3*64)

  // staging coords for this thread (2 chunks x (row, granule))
  int sr0 = t >> 3, sg0 = t & 7;              // chunk 0: rows 0..31
  int sr1 = sr0 + 32;                         // chunk 1: rows 32..63

  // persistent Q fragments (wave's 16 q-rows)
  s16x8 qf[2];
#pragma unroll
  for (int ks = 0; ks < 2; ks++)
    qf[ks] = *(const s16x8*)&qkv[(size_t)(b * S + q0 + wave * 16 + l15) * 2304
                                 + h * 64 + ks * 32 + l4 * 8];

  // ---- prologue: stage all 4 tiles for k0 = 0 ----
  {
    *(s16x8*)&Ks[swz8(sr0, sg0)] =
        *(const s16x8*)&qkv[(size_t)(b * S + sr0) * 2304 + 768 + h * 64 + sg0 * 8];
    *(s16x8*)&Ks[swz8(sr1, sg0)] =
        *(const s16x8*)&qkv[(size_t)(b * S + sr1) * 2304 + 768 + h * 64 + sg0 * 8];
    *(s16x8*)&Vs[swz8(sr0, sg0)] =
        *(const s16x8*)&vt[((size_t)bh * 64 + sr0) * S + sg0 * 8];
    *(s16x8*)&Vs[swz8(sr1, sg0)] =
        *(const s16x8*)&vt[((size_t)bh * 64 + sr1) * S + sg0 * 8];
    *(s16x8*)&QPs[swz8(sr0, sg0)] =
        *(const s16x8*)&QP[((size_t)bh * 512 + q0 + sr0) * 512 + 448 + sg0 * 8];
    *(s16x8*)&QPs[swz8(sr1, sg0)] =
        *(const s16x8*)&QP[((size_t)bh * 512 + q0 + sr1) * 512 + 448 + sg0 * 8];
    *(s16x8*)&KPs[swz8(sr0, sg0)] =
        *(const s16x8*)&KP[((size_t)bh * 512 + sr0) * 512 + (448 - q0) + sg0 * 8];
    *(s16x8*)&KPs[swz8(sr1, sg0)] =
        *(const s16x8*)&KP[((size_t)bh * 512 + sr1) * 512 + (448 - q0) + sg0 * 8];
  }
  __syncthreads();                                    // tile 0 visible

  float m[4], l[4];
  f32x4 accO[4];
#pragma unroll
  for (int j = 0; j < 4; j++) { m[j] = -1e30f; l[j] = 0.f; }
#pragma unroll
  for (int n = 0; n < 4; n++) accO[n] = (f32x4){0.f, 0.f, 0.f, 0.f};

  for (int k0 = 0; k0 < S; k0 += 64) {
    int k0n = k0 + 64;
    bool pf = (k0n < S);

    // ---- T14: issue next tile's QP/KP stream loads into regs ----
    s16x8 pfQ0, pfQ1, pfK0, pfK1;
    if (pf) {
      pfQ0 = *(const s16x8*)&QP[((size_t)bh * 512 + q0 + sr0) * 512 + (448 - k0n) + sg0 * 8];
      pfQ1 = *(const s16x8*)&QP[((size_t)bh * 512 + q0 + sr1) * 512 + (448 - k0n) + sg0 * 8];
      pfK0 = *(const s16x8*)&KP[((size_t)bh * 512 + k0n + sr0) * 512 + (448 - q0) + sg0 * 8];
      pfK1 = *(const s16x8*)&KP[((size_t)bh * 512 + k0n + sr1) * 512 + (448 - q0) + sg0 * 8];
    }

    // ---- c2c MFMAs ----
    f32x4 c2c[4] = {};
#pragma unroll
    for (int ks = 0; ks < 2; ks++) {
      int g = ks * 4 + l4;
#pragma unroll
      for (int n = 0; n < 4; n++) {
        s16x8 bk = *(const s16x8*)&Ks[swz8(n * 16 + l15, g)];
        c2c[n] = __builtin_amdgcn_mfma_f32_16x16x32_bf16(qf[ks], bk, c2c[n], 0, 0, 0);
      }
    }

    // ---- score assembly + online softmax ----
    float p[4][4];
    float rmax[4];
#pragma unroll
    for (int j = 0; j < 4; j++) rmax[j] = -1e30f;
#pragma unroll
    for (int n = 0; n < 4; n++) {
      int ik = n * 16 + l15;
      bool msk = (tok[b * S + k0 + ik] == 0);
      int ccp = 63 - ik;             // QPs col for this k
#pragma unroll
      for (int j = 0; j < 4; j++) {
        int iq = wave * 16 + (l4 << 2) + j;
        float sc = c2c[n][j]
                 + bf2f(QPs[swze(iq, ccp)])
                 + bf2f(KPs[swze(ik, 63 - iq)]);
        sc *= scale;
        if (msk) sc = -1e9f;
        p[n][j] = sc;
        rmax[j] = fmaxf(rmax[j], sc);
      }
    }
#pragma unroll
    for (int o = 8; o > 0; o >>= 1)
#pragma unroll
      for (int j = 0; j < 4; j++)
        rmax[j] = fmaxf(rmax[j], __shfl_xor(rmax[j], o, 64));
    float al[4];
#pragma unroll
    for (int j = 0; j < 4; j++) {
      float mn = fmaxf(m[j], rmax[j]);
      al[j] = __expf(m[j] - mn);
      m[j] = mn;
    }
    float rs[4] = {0.f, 0.f, 0.f, 0.f};
#pragma unroll
    for (int n = 0; n < 4; n++)
#pragma unroll
      for (int j = 0; j < 4; j++) {
        p[n][j] = __expf(p[n][j] - m[j]);
        rs[j] += p[n][j];
      }
#pragma unroll
    for (int o = 8; o > 0; o >>= 1)
#pragma unroll
      for (int j = 0; j < 4; j++) rs[j] += __shfl_xor(rs[j], o, 64);
#pragma unroll
    for (int j = 0; j < 4; j++) l[j] = l[j] * al[j] + rs[j];
#pragma unroll
    for (int n = 0; n < 4; n++)
#pragma unroll
      for (int j = 0; j < 4; j++) accO[n][j] *= al[j];

    // ---- P -> Ps ----
    {
      int rw = wave * 16 + (l4 << 2);
#pragma unroll
      for (int n = 0; n < 4; n++)
#pragma unroll
        for (int j = 0; j < 4; j++)
          Ps[swze(rw + j, n * 16 + l15)] = f2bf(p[n][j]);
    }
    __syncthreads();                                  // (2) P visible

    // ---- PV: accO += P @ V ----
#pragma unroll
    for (int ks = 0; ks < 2; ks++) {
      int g = ks * 4 + l4;
      s16x8 ap = *(const s16x8*)&Ps[swz8(wave * 16 + l15, g)];
#pragma unroll
      for (int n = 0; n < 4; n++) {
        s16x8 bv2 = *(const s16x8*)&Vs[swz8(n * 16 + l15, g)];
        accO[n] = __builtin_amdgcn_mfma_f32_16x16x32_bf16(ap, bv2, accO[n], 0, 0, 0);
      }
    }
    __syncthreads();                                  // (3) all reads done

    // ---- tail staging for k0n: prefetched QP/KP + sync K/V (L2-hot) ----
    if (pf) {
      *(s16x8*)&QPs[swz8(sr0, sg0)] = pfQ0;
      *(s16x8*)&QPs[swz8(sr1, sg0)] = pfQ1;
      *(s16x8*)&KPs[swz8(sr0, sg0)] = pfK0;
      *(s16x8*)&KPs[swz8(sr1, sg0)] = pfK1;
      *(s16x8*)&Ks[swz8(sr0, sg0)] =
          *(const s16x8*)&qkv[(size_t)(b * S + k0n + sr0) * 2304 + 768 + h * 64 + sg0 * 8];
      *(s16x8*)&Ks[swz8(sr1, sg0)] =
          *(const s16x8*)&qkv[(size_t)(b * S + k0n + sr1) * 2304 + 768 + h * 64 + sg0 * 8];
      *(s16x8*)&Vs[swz8(sr0, sg0)] =
          *(const s16x8*)&vt[((size_t)bh * 64 + sr0) * S + k0n + sg0 * 8];
      *(s16x8*)&Vs[swz8(sr1, sg0)] =
          *(const s16x8*)&vt[((size_t)bh * 64 + sr1) * S + k0n + sg0 * 8];
      __syncthreads();                                // (1) next tile visible
    }
  }

  // ---- epilogue: O = accO / l ----
#pragma unroll
  for (int n = 0; n < 4; n++) {
    int dd = h * 64 + n * 16 + l15;
#pragma unroll
    for (int j = 0; j < 4; j++) {
      int iq = q0 + wave * 16 + (l4 << 2) + j;
      ctx[(size_t)(b * S + iq) * HID + dd] = f2bf(accO[n][j] / l[j]);
    }
  }
}

// ---------------------------------------------------------------------------
extern "C" void kernel_launch(void* const* d_in, const int* in_sizes, int n_in,
                              void* d_out, int out_size, void* d_ws,
                              size_t ws_size, hipStream_t stream) {
  (void)in_sizes; (void)n_in; (void)out_size; (void)ws_size;
  const int*   tok     = (const int*)d_in[0];
  const int*   seg     = (const int*)d_in[1];
  const float* tok_emb = (const float*)d_in[2];
  const float* seg_emb = (const float*)d_in[3];
  const float* Wq  = (const float*)d_in[4];
  const float* bq  = (const float*)d_in[5];
  const float* Wk  = (const float*)d_in[6];
  const float* bk  = (const float*)d_in[7];
  const float* Wv  = (const float*)d_in[8];
  const float* bv  = (const float*)d_in[9];
  const float* Wo  = (const float*)d_in[10];
  const float* bo  = (const float*)d_in[11];
  const float* Wpk = (const float*)d_in[12];
  const float* Wpq = (const float*)d_in[13];
  const float* rel = (const float*)d_in[14];
  const float* ln1g = (const float*)d_in[15];
  const float* ln1b = (const float*)d_in[16];
  const float* ln2g = (const float*)d_in[17];
  const float* ln2b = (const float*)d_in[18];
  const float* W1  = (const float*)d_in[19];
  const float* b1  = (const float*)d_in[20];
  const float* W2  = (const float*)d_in[21];
  const float* b2  = (const float*)d_in[22];
  const float* lnfg = (const float*)d_in[23];
  const float* lnfb = (const float*)d_in[24];
  float* out = (float*)d_out;

  // ---- workspace layout (~281 MB of ~528 MB) ----
  char* base = (char*)d_ws;
  size_t off = 0;
  auto alloc = [&](size_t bytes) -> void* {
    void* p = base + off;
    off += (bytes + 255) & ~(size_t)255;
    return p;
  };
  const size_t XSZ = (size_t)NTOK * HID;
  float* x = (float*)alloc(XSZ * 4);
  us* qkv16 = (us*)alloc((size_t)NTOK * 2304 * 2);
  us* pkq16 = (us*)alloc((size_t)M2 * 1536 * 2);
  us* vt16  = (us*)alloc(XSZ * 2);
  us* act16 = (us*)alloc(XSZ * 2);
  us* ff16  = (us*)alloc((size_t)NTOK * FF * 2);
  us* rel16 = (us*)alloc((size_t)M2 * HID * 2);
  us* wt6   = (us*)alloc((size_t)6 * HID * HID * 2);
  us* wt1   = (us*)alloc((size_t)HID * FF * 2);
  us* wt2   = (us*)alloc((size_t)HID * FF * 2);
  float* skbuf = (float*)alloc((size_t)2 * NTOK * HID * 4);
  float* bqkv  = (float*)alloc((size_t)L * 2304 * 4);
  us* QP = (us*)alloc((size_t)B * NH * S * 512 * 2);   // 50.33 MB
  us* KP = (us*)alloc((size_t)B * NH * S * 512 * 2);   // 50.33 MB

  const size_t WSQ = (size_t)HID * HID;

  embed_kernel<<<NTOK, 256, 0, stream>>>(tok, seg, tok_emb, seg_emb, x);
  concat_bias<<<(L * 2304 + 255) / 256, 256, 0, stream>>>(bq, bk, bv, bqkv);
  ln_kernel<1><<<NTOK / 4, 256, 0, stream>>>(x, act16, ln1g, ln1b, NTOK);

  for (int l = 0; l < L; l++) {
    // ---- merged weight prep (slots: 0=q 1=k 2=v 3=o 4=pk 5=pq) ----
    weight_prep<<<8832, 256, 0, stream>>>(
        Wq + l * WSQ, Wk + l * WSQ, Wv + l * WSQ, Wo + l * WSQ,
        Wpk + l * WSQ, Wpq + l * WSQ, W1 + (size_t)l * HID * FF,
        W2 + (size_t)l * FF * HID, rel + (size_t)l * M2 * HID,
        wt6, wt1, wt2, rel16);

    // ---- attention ----
    mfma_gemm<128, 1, 0, 0><<<dim3(2304 / 128, NTOK / 128, 1), 256, 0, stream>>>(
        act16, wt6, bqkv + l * 2304, nullptr, qkv16, NTOK, HID, 2304, HID);
    mfma_gemm<64, 1, 0, 0><<<dim3(1536 / 64, M2 / 128, 1), 256, 0, stream>>>(
        rel16, wt6 + 4 * WSQ, nullptr, nullptr, pkq16, M2, HID, 1536, HID);
    transpose_v<<<dim3(S / 32, D / 32, B * NH), 256, 0, stream>>>(qkv16, vt16);
    qpkp_kernel<<<dim3(S / 64, B * NH, 2), 256, 0, stream>>>(
        qkv16, pkq16, QP, KP);
    flash_attn<<<dim3(S / 64, B * NH), 256, 0, stream>>>(
        qkv16, QP, KP, vt16, tok, act16);

    // ---- O-proj: split-K x2 partials + fused (bias + residual + LN2) ----
    mfma_gemm<64, 0, 0, 1><<<dim3(HID / 64, NTOK / 128, 2), 256, 0, stream>>>(
        act16, wt6 + 3 * WSQ, nullptr, nullptr, skbuf, NTOK, HID, HID, HID / 2);
    combine_ln<0><<<NTOK, 256, 0, stream>>>(
        skbuf, x, bo + l * HID, ln2g + l * HID, ln2b + l * HID, act16);

    // ---- feedforward ----
    mfma_gemm<128, 1, 1, 0><<<dim3(FF / 128, NTOK / 128, 1), 256, 0, stream>>>(
        act16, wt1, b1 + l * FF, nullptr, ff16, NTOK, HID, FF, HID);
    mfma_gemm<64, 0, 0, 1><<<dim3(HID / 64, NTOK / 128, 2), 256, 0, stream>>>(
        ff16, wt2, nullptr, nullptr, skbuf, NTOK, FF, HID, FF / 2);
    if (l < L - 1) {
      combine_ln<0><<<NTOK, 256, 0, stream>>>(
          skbuf, x, b2 + l * HID, ln1g + (l + 1) * HID, ln1b + (l + 1) * HID,
          act16);
    } else {
      combine_ln<1><<<NTOK, 256, 0, stream>>>(
          skbuf, x, b2 + l * HID, lnfg, lnfb, out);
    }
  }
}

// Round 16
// 3779.427 us; speedup vs baseline: 1.1399x; 1.1351x over previous
//
#include <hip/hip_runtime.h>
#include <hip/hip_bf16.h>
#include <cstddef>
#include <cstdint>

// ---------------------------------------------------------------------------
// DeBERTa forward, MI355X. Round 16: best-of composition.
//  - flash_attn: r10 body verbatim (82.5us, no prefetch)
//  - O-proj split-K x2 + combine_ln-fused bias+residual+LN2 (r11 win)
//  - NEW: BK=64 swizzled-tile GEMM for QKV & W1 (half the barriers/K-loop)
// B=8 S=512 HID=768 L=12 NH=12 D=64 FF=3072 2M=1024
// ---------------------------------------------------------------------------

constexpr int B   = 8;
constexpr int S   = 512;
constexpr int HID = 768;
constexpr int L   = 12;
constexpr int NH  = 12;
constexpr int D   = 64;
constexpr int FF  = 3072;
constexpr int M2  = 1024;          // 2*M
constexpr int NTOK = B * S;        // 4096

using f32x4 = __attribute__((ext_vector_type(4))) float;
using s16x8 = __attribute__((ext_vector_type(8))) short;
typedef unsigned short us;

__device__ inline float wave_sum(float v) {
#pragma unroll
  for (int o = 32; o > 0; o >>= 1) v += __shfl_xor(v, o, 64);
  return v;
}
__device__ inline us f2bf(float f) {
  __hip_bfloat16 h = __float2bfloat16(f);
  return *reinterpret_cast<us*>(&h);
}
__device__ inline float bf2f(us u) {
  union { unsigned int i; float f; } x;
  x.i = ((unsigned int)u) << 16;
  return x.f;
}
// swizzled elem offset into a [rows][64] bf16 tile (128B rows): granule^row&7
__device__ inline int swz8(int row, int g) {
  return row * 64 + ((g ^ (row & 7)) << 3);
}
// scalar element read index for swizzled tile: element c of row r
__device__ inline int swze(int r, int c) {
  return r * 64 + ((((c >> 3) ^ (r & 7)) << 3) | (c & 7));
}
#define GLOAD16(gp, lp)                                                  \
  __builtin_amdgcn_global_load_lds(                                     \
      (const __attribute__((address_space(1))) void*)(gp),              \
      (__attribute__((address_space(3))) void*)(lp), 16, 0, 0)

// ---- embeddings -------------------------------------------------------------
__global__ void embed_kernel(const int* __restrict__ tok,
                             const int* __restrict__ seg,
                             const float* __restrict__ tok_emb,
                             const float* __restrict__ seg_emb,
                             float* __restrict__ x) {
  int row = blockIdx.x;
  int s = row & (S - 1);
  int t = tok[row];
  int sg = seg[row];
  for (int c = threadIdx.x; c < HID; c += blockDim.x) {
    int i = c >> 1;
    float ang = (float)s * powf(10000.0f, -2.0f * (float)i / (float)HID);
    float pe = (c & 1) ? cosf(ang) : sinf(ang);
    x[(size_t)row * HID + c] = tok_emb[(size_t)t * HID + c] + pe
                             + seg_emb[(size_t)sg * HID + c];
  }
}

// ---- layernorm (one wave per row) -------------------------------------------
template <int BF16OUT>
__global__ __launch_bounds__(256)
void ln_kernel(const float* __restrict__ in, void* __restrict__ outp,
               const float* __restrict__ g, const float* __restrict__ b,
               int nrows) {
  int wave = threadIdx.x >> 6, lane = threadIdx.x & 63;
  int row = blockIdx.x * 4 + wave;
  if (row >= nrows) return;
  const float* xr = in + (size_t)row * HID;
  float v[12];
  float s = 0.f;
#pragma unroll
  for (int i = 0; i < 12; i++) { v[i] = xr[lane + i * 64]; s += v[i]; }
  s = wave_sum(s);
  float mu = s * (1.0f / HID);
  float ss = 0.f;
#pragma unroll
  for (int i = 0; i < 12; i++) { float d = v[i] - mu; ss += d * d; }
  ss = wave_sum(ss);
  float inv = rsqrtf(ss * (1.0f / HID) + 1e-5f);
#pragma unroll
  for (int i = 0; i < 12; i++) {
    int c = lane + i * 64;
    float o = (v[i] - mu) * inv * g[c] + b[c];
    if (BF16OUT)
      ((us*)outp)[(size_t)row * HID + c] = f2bf(o);
    else
      ((float*)outp)[(size_t)row * HID + c] = o;
  }
}

// ---- merged weight prep: 6 square transposes + W1 + W2 + rel conv -----------
__global__ __launch_bounds__(256)
void weight_prep(const float* Wq, const float* Wk, const float* Wv,
                 const float* Wo, const float* Wpk, const float* Wpq,
                 const float* W1s, const float* W2s, const float* rel,
                 us* __restrict__ wt6, us* __restrict__ wt1,
                 us* __restrict__ wt2, us* __restrict__ rel16) {
  int bz = blockIdx.x;
  if (bz >= 8064) {                 // rel f32 -> bf16, 4/thread
    int i = (bz - 8064) * 1024 + threadIdx.x * 4;
    f32x4 v = *(const f32x4*)&rel[i];
#pragma unroll
    for (int j = 0; j < 4; j++) rel16[i + j] = f2bf(v[j]);
    return;
  }
  __shared__ float tile[32][33];
  int tx = threadIdx.x & 31, ty = threadIdx.x >> 5;
  const float* src;
  us* dst;
  int N, K, nt, kt;
  if (bz < 3456) {                  // 6 square [HID,HID]
    int z = bz / 576, r = bz % 576;
    const float* srcs[6] = {Wq, Wk, Wv, Wo, Wpk, Wpq};
    src = srcs[z];
    dst = wt6 + (size_t)z * HID * HID;
    N = HID; K = HID;
    nt = (r % 24) * 32; kt = (r / 24) * 32;
  } else if (bz < 5760) {           // W1 [768,3072] -> [3072,768]
    int r = bz - 3456;
    src = W1s; dst = wt1; N = FF; K = HID;
    nt = (r % 96) * 32; kt = (r / 96) * 32;
  } else {                          // W2 [3072,768] -> [768,3072]
    int r = bz - 5760;
    src = W2s; dst = wt2; N = HID; K = FF;
    nt = (r % 24) * 32; kt = (r / 24) * 32;
  }
#pragma unroll
  for (int i = 0; i < 4; i++)
    tile[ty + i * 8][tx] = src[(size_t)(kt + ty + i * 8) * N + nt + tx];
  __syncthreads();
#pragma unroll
  for (int i = 0; i < 4; i++)
    dst[(size_t)(nt + ty + i * 8) * K + kt + tx] = f2bf(tile[tx][ty + i * 8]);
}

__global__ void concat_bias(const float* __restrict__ bq,
                            const float* __restrict__ bk,
                            const float* __restrict__ bv,
                            float* __restrict__ bqkv) {
  int i = blockIdx.x * 256 + threadIdx.x;
  if (i >= L * 2304) return;
  int l = i / 2304, c = i % 2304;
  float v = (c < 768) ? bq[l * 768 + c]
          : (c < 1536) ? bk[l * 768 + c - 768] : bv[l * 768 + c - 1536];
  bqkv[i] = v;
}

// ---- bf16 MFMA GEMM, 128xTN tile, BK=32 (linear) or BK=64 (swizzled) --------
template <int TN, int BK, int OUT_BF16, int GELU, int PARTIAL>
__global__ __launch_bounds__(256)
void mfma_gemm(const us* __restrict__ A, const us* __restrict__ Bt,
               const float* __restrict__ bias, const float* __restrict__ res,
               void* __restrict__ C, int Mr, int K, int N, int Kc) {
  constexpr int NW = TN / 32;
  __shared__ us As[128 * BK];
  __shared__ us Bs[TN * BK];
  int t = threadIdx.x, wave = t >> 6, lane = t & 63;
  int r0 = blockIdx.y * 128, n0 = blockIdx.x * TN;
  int kb = blockIdx.z * Kc;
  int wr = (wave >> 1) * 64;
  int wc = (wave & 1) * (TN / 2);

  f32x4 acc[4][NW] = {};
  int srow = lane >> 2, selem = (lane & 3) * 8;

  for (int k0 = kb; k0 < kb + Kc; k0 += BK) {
    __syncthreads();
    if constexpr (BK == 64) {
      // [rows][64] tiles, 128B rows, XOR-swizzled via pre-swizzled source
#pragma unroll
      for (int i = 0; i < 4; i++) {
        int slot = i * 64 + lane;
        int rr = slot >> 3;                       // 0..31 (wave-relative row)
        int sc = (((slot & 7) ^ (rr & 7)) << 3);  // pre-swizzled granule
        const us* gA = A + (size_t)(r0 + wave * 32 + rr) * K + k0 + sc;
        GLOAD16(gA, &As[(wave * 32) * 64 + i * 512]);
        const us* gB = Bt + (size_t)(n0 + wave * 32 + rr) * K + k0 + sc;
        GLOAD16(gB, &Bs[(wave * 32) * 64 + i * 512]);
      }
    } else {
      const us* gA = A + (size_t)(r0 + wave * 32 + srow) * K + k0 + selem;
      us* lA = &As[(wave * 32) * 32];
      GLOAD16(gA, lA);
      GLOAD16(gA + (size_t)16 * K, lA + 16 * 32);
      if (TN == 128) {
        const us* gB = Bt + (size_t)(n0 + wave * 32 + srow) * K + k0 + selem;
        us* lB = &Bs[(wave * 32) * 32];
        GLOAD16(gB, lB);
        GLOAD16(gB + (size_t)16 * K, lB + 16 * 32);
      } else {
        const us* gB = Bt + (size_t)(n0 + wave * 16 + srow) * K + k0 + selem;
        GLOAD16(gB, &Bs[(wave * 16) * 32]);
      }
    }
    __syncthreads();

    if constexpr (BK == 64) {
#pragma unroll
      for (int ks = 0; ks < 2; ks++) {
        int g = ks * 4 + (lane >> 4);
        s16x8 af[4], bf[NW];
#pragma unroll
        for (int m = 0; m < 4; m++)
          af[m] = *(const s16x8*)&As[swz8(wr + m * 16 + (lane & 15), g)];
#pragma unroll
        for (int n = 0; n < NW; n++)
          bf[n] = *(const s16x8*)&Bs[swz8(wc + n * 16 + (lane & 15), g)];
#pragma unroll
        for (int m = 0; m < 4; m++)
#pragma unroll
          for (int n = 0; n < NW; n++)
            acc[m][n] = __builtin_amdgcn_mfma_f32_16x16x32_bf16(af[m], bf[n],
                                                                acc[m][n], 0, 0, 0);
      }
    } else {
      s16x8 af[4], bf[NW];
#pragma unroll
      for (int m = 0; m < 4; m++)
        af[m] = *(const s16x8*)&As[(wr + m * 16 + (lane & 15)) * 32 + (lane >> 4) * 8];
#pragma unroll
      for (int n = 0; n < NW; n++)
        bf[n] = *(const s16x8*)&Bs[(wc + n * 16 + (lane & 15)) * 32 + (lane >> 4) * 8];
#pragma unroll
      for (int m = 0; m < 4; m++)
#pragma unroll
        for (int n = 0; n < NW; n++)
          acc[m][n] = __builtin_amdgcn_mfma_f32_16x16x32_bf16(af[m], bf[n],
                                                              acc[m][n], 0, 0, 0);
    }
  }

  if (PARTIAL) {
    float* Cp = (float*)C + (size_t)blockIdx.z * Mr * N;
#pragma unroll
    for (int n = 0; n < NW; n++) {
      int c = n0 + wc + n * 16 + (lane & 15);
#pragma unroll
      for (int m = 0; m < 4; m++) {
        int rb = r0 + wr + m * 16 + ((lane >> 4) << 2);
#pragma unroll
        for (int j = 0; j < 4; j++)
          Cp[(size_t)(rb + j) * N + c] = acc[m][n][j];
      }
    }
    return;
  }
#pragma unroll
  for (int n = 0; n < NW; n++) {
    int c = n0 + wc + n * 16 + (lane & 15);
    float bv = bias ? bias[c] : 0.f;
#pragma unroll
    for (int m = 0; m < 4; m++) {
      int rb = r0 + wr + m * 16 + ((lane >> 4) << 2);
#pragma unroll
      for (int j = 0; j < 4; j++) {
        int r = rb + j;
        float val = acc[m][n][j] + bv;
        if (GELU) val = 0.5f * val * (1.0f + erff(val * 0.70710678118654752f));
        if (res)  val += res[(size_t)r * N + c];
        if (OUT_BF16)
          ((us*)C)[(size_t)r * N + c] = f2bf(val);
        else
          ((float*)C)[(size_t)r * N + c] = val;
      }
    }
  }
}

// ---- split-K combine + residual + LN ----------------------------------------
template <int LAST>
__global__ __launch_bounds__(256)
void combine_ln(const float* __restrict__ part,   // [2][NTOK][HID]
                float* __restrict__ x, const float* __restrict__ bias,
                const float* __restrict__ g, const float* __restrict__ bb,
                void* __restrict__ outp) {
  int row = blockIdx.x, t = threadIdx.x;
  int wave = t >> 6, lane = t & 63;
  __shared__ float red[4];
  float v[3];
  float s = 0.f;
#pragma unroll
  for (int i = 0; i < 3; i++) {
    int c = t + i * 256;
    size_t idx = (size_t)row * HID + c;
    float val = x[idx] + part[idx] + part[(size_t)NTOK * HID + idx] + bias[c];
    if (!LAST) x[idx] = val;
    v[i] = val;
    s += val;
  }
  s = wave_sum(s);
  if (lane == 0) red[wave] = s;
  __syncthreads();
  float mu = (red[0] + red[1] + red[2] + red[3]) * (1.0f / HID);
  float ss = 0.f;
#pragma unroll
  for (int i = 0; i < 3; i++) { float d = v[i] - mu; ss += d * d; }
  ss = wave_sum(ss);
  __syncthreads();
  if (lane == 0) red[wave] = ss;
  __syncthreads();
  float inv = rsqrtf((red[0] + red[1] + red[2] + red[3]) * (1.0f / HID) + 1e-5f);
#pragma unroll
  for (int i = 0; i < 3; i++) {
    int c = t + i * 256;
    float o = (v[i] - mu) * inv * g[c] + bb[c];
    if (LAST)
      ((float*)outp)[(size_t)row * HID + c] = o;
    else
      ((us*)outp)[(size_t)row * HID + c] = f2bf(o);
  }
}

// ---- V transpose from fused qkv ----------------------------------------------
__global__ __launch_bounds__(256)
void transpose_v(const us* __restrict__ qkv, us* __restrict__ vt) {
  __shared__ us tile[32][34];
  int bh = blockIdx.z;
  int b = bh / NH, h = bh % NH;
  int s0 = blockIdx.x * 32, d0 = blockIdx.y * 32;
  int tx = threadIdx.x & 31, ty = threadIdx.x >> 5;
#pragma unroll
  for (int i = 0; i < 4; i++)
    tile[ty + i * 8][tx] =
        qkv[(size_t)(b * S + s0 + ty + i * 8) * 2304 + 1536 + h * 64 + d0 + tx];
  __syncthreads();
#pragma unroll
  for (int i = 0; i < 4; i++)
    vt[((size_t)bh * 64 + d0 + ty + i * 8) * S + s0 + tx] = tile[tx][ty + i * 8];
}

// ---- QP/KP precompute: banded GEMM with shifted store ------------------------
// z=0: QP[q,j] = Q_q . pk[q+1+j]   z=1: KP[k,j] = K_k . pq[k+1+j]
__global__ __launch_bounds__(256)
void qpkp_kernel(const us* __restrict__ qkv, const us* __restrict__ pkq,
                 us* __restrict__ QP, us* __restrict__ KP) {
  __shared__ us As[64 * 64];   // A tile (swz)
  __shared__ us Bs[64 * 64];   // B chunk (swz)
  int t = threadIdx.x, wave = t >> 6, lane = t & 63;
  int l15 = lane & 15, l4 = lane >> 4;
  int t0 = blockIdx.x * 64;
  int bh = blockIdx.y;              // 0..95
  int b = bh / NH, h = bh % NH;
  int z = blockIdx.z;
  int zoff = z * 768;
  us* outp = (z ? KP : QP) + ((size_t)bh * 512 + t0) * 512;

  // stage A (64 rows of Q or K for this head)
#pragma unroll
  for (int i = 0; i < 2; i++) {
    int c = t + i * 256;
    int r = c >> 3, g = c & 7;
    *(s16x8*)&As[swz8(r, g)] =
        *(const s16x8*)&qkv[(size_t)(b * S + t0 + r) * 2304 + zoff + h * 64 + g * 8];
  }

  s16x8 af[2];
  for (int c = 0; c < 9; c++) {
    // stage B chunk: pk/pq rows t0+1+c*64 .. +63 (clamped; clamped rows unused)
#pragma unroll
    for (int i = 0; i < 2; i++) {
      int cc = t + i * 256;
      int rr = cc >> 3, g = cc & 7;
      int rb = t0 + 1 + c * 64 + rr;
      rb = rb > M2 - 1 ? M2 - 1 : rb;
      *(s16x8*)&Bs[swz8(rr, g)] =
          *(const s16x8*)&pkq[(size_t)rb * 1536 + zoff + h * 64 + g * 8];
    }
    __syncthreads();
    if (c == 0) {
#pragma unroll
      for (int ks = 0; ks < 2; ks++)
        af[ks] = *(const s16x8*)&As[swz8(wave * 16 + l15, ks * 4 + l4)];
    }
    f32x4 acc[4] = {};
#pragma unroll
    for (int ks = 0; ks < 2; ks++)
#pragma unroll
      for (int n = 0; n < 4; n++) {
        s16x8 bf = *(const s16x8*)&Bs[swz8(n * 16 + l15, ks * 4 + l4)];
        acc[n] = __builtin_amdgcn_mfma_f32_16x16x32_bf16(af[ks], bf, acc[n], 0, 0, 0);
      }
    // shifted store: out[row=iq][j=rc'-iq] for 0<=j<512
#pragma unroll
    for (int n = 0; n < 4; n++) {
      int rcp = c * 64 + n * 16 + l15;
#pragma unroll
      for (int jj = 0; jj < 4; jj++) {
        int iq = wave * 16 + (l4 << 2) + jj;
        int j = rcp - iq;
        if ((unsigned)j < 512u)
          outp[(size_t)iq * 512 + j] = f2bf(acc[n][jj]);
      }
    }
    __syncthreads();
  }
}

// ---- flash attention (r10 body, verbatim): table scores, 3 barriers, 40KB ----
// scores[q,k] = (c2c + QP[q,511-k] + KP[k,511-q]) * scale, masked.
__global__ __launch_bounds__(256, 4)
void flash_attn(const us* __restrict__ qkv,
                const us* __restrict__ QP,    // [96*512][512]
                const us* __restrict__ KP,
                const us* __restrict__ vt,    // [B*NH*64][S]
                const int* __restrict__ tok,
                us* __restrict__ ctx) {
  __shared__ us Ks[4096];    // K tile (swz)
  __shared__ us Vs[4096];    // V^T tile (swz)
  __shared__ us QPs[4096];   // QP slab tile (swz)
  __shared__ us KPs[4096];   // KP slab tile (swz)
  __shared__ us Ps[4096];    // P (swz)

  int t = threadIdx.x, wave = t >> 6, lane = t & 63;
  int bh = blockIdx.y;
  int b = bh / NH, h = bh % NH;
  int q0 = blockIdx.x * 64;
  int l15 = lane & 15, l4 = lane >> 4;
  const float scale = 0.07216878364870323f;   // 1/sqrt(3*64)

  // persistent Q fragments (wave's 16 q-rows)
  s16x8 qf[2];
#pragma unroll
  for (int ks = 0; ks < 2; ks++)
    qf[ks] = *(const s16x8*)&qkv[(size_t)(b * S + q0 + wave * 16 + l15) * 2304
                                 + h * 64 + ks * 32 + l4 * 8];

  float m[4], l[4];
  f32x4 accO[4];
#pragma unroll
  for (int j = 0; j < 4; j++) { m[j] = -1e30f; l[j] = 0.f; }
#pragma unroll
  for (int n = 0; n < 4; n++) accO[n] = (f32x4){0.f, 0.f, 0.f, 0.f};

  for (int k0 = 0; k0 < S; k0 += 64) {
    // ---- stage K, V^T, QP tile, KP tile (all swizzled) ----
#pragma unroll
    for (int i = 0; i < 2; i++) {
      int c = t + i * 256;
      int r = c >> 3, g = c & 7;
      *(s16x8*)&Ks[swz8(r, g)] =
          *(const s16x8*)&qkv[(size_t)(b * S + k0 + r) * 2304 + 768 + h * 64 + g * 8];
      *(s16x8*)&Vs[swz8(r, g)] =
          *(const s16x8*)&vt[((size_t)bh * 64 + r) * S + k0 + g * 8];
      *(s16x8*)&QPs[swz8(r, g)] =
          *(const s16x8*)&QP[((size_t)bh * 512 + q0 + r) * 512 + (448 - k0) + g * 8];
      *(s16x8*)&KPs[swz8(r, g)] =
          *(const s16x8*)&KP[((size_t)bh * 512 + k0 + r) * 512 + (448 - q0) + g * 8];
    }
    __syncthreads();                                  // (1) staging visible

    // ---- c2c MFMAs ----
    f32x4 c2c[4] = {};
#pragma unroll
    for (int ks = 0; ks < 2; ks++) {
      int g = ks * 4 + l4;
#pragma unroll
      for (int n = 0; n < 4; n++) {
        s16x8 bk = *(const s16x8*)&Ks[swz8(n * 16 + l15, g)];
        c2c[n] = __builtin_amdgcn_mfma_f32_16x16x32_bf16(qf[ks], bk, c2c[n], 0, 0, 0);
      }
    }

    // ---- score assembly + online softmax ----
    float p[4][4];
    float rmax[4];
#pragma unroll
    for (int j = 0; j < 4; j++) rmax[j] = -1e30f;
#pragma unroll
    for (int n = 0; n < 4; n++) {
      int ik = n * 16 + l15;
      bool msk = (tok[b * S + k0 + ik] == 0);
      int ccp = 63 - ik;             // QPs col for this k
#pragma unroll
      for (int j = 0; j < 4; j++) {
        int iq = wave * 16 + (l4 << 2) + j;
        float sc = c2c[n][j]
                 + bf2f(QPs[swze(iq, ccp)])
                 + bf2f(KPs[swze(ik, 63 - iq)]);
        sc *= scale;
        if (msk) sc = -1e9f;
        p[n][j] = sc;
        rmax[j] = fmaxf(rmax[j], sc);
      }
    }
#pragma unroll
    for (int o = 8; o > 0; o >>= 1)
#pragma unroll
      for (int j = 0; j < 4; j++)
        rmax[j] = fmaxf(rmax[j], __shfl_xor(rmax[j], o, 64));
    float al[4];
#pragma unroll
    for (int j = 0; j < 4; j++) {
      float mn = fmaxf(m[j], rmax[j]);
      al[j] = __expf(m[j] - mn);
      m[j] = mn;
    }
    float rs[4] = {0.f, 0.f, 0.f, 0.f};
#pragma unroll
    for (int n = 0; n < 4; n++)
#pragma unroll
      for (int j = 0; j < 4; j++) {
        p[n][j] = __expf(p[n][j] - m[j]);
        rs[j] += p[n][j];
      }
#pragma unroll
    for (int o = 8; o > 0; o >>= 1)
#pragma unroll
      for (int j = 0; j < 4; j++) rs[j] += __shfl_xor(rs[j], o, 64);
#pragma unroll
    for (int j = 0; j < 4; j++) l[j] = l[j] * al[j] + rs[j];
#pragma unroll
    for (int n = 0; n < 4; n++)
#pragma unroll
      for (int j = 0; j < 4; j++) accO[n][j] *= al[j];

    // ---- P -> Ps ----
    {
      int rw = wave * 16 + (l4 << 2);
#pragma unroll
      for (int n = 0; n < 4; n++)
#pragma unroll
        for (int j = 0; j < 4; j++)
          Ps[swze(rw + j, n * 16 + l15)] = f2bf(p[n][j]);
    }
    __syncthreads();                                  // (2) P visible

    // ---- PV: accO += P @ V ----
#pragma unroll
    for (int ks = 0; ks < 2; ks++) {
      int g = ks * 4 + l4;
      s16x8 ap = *(const s16x8*)&Ps[swz8(wave * 16 + l15, g)];
#pragma unroll
      for (int n = 0; n < 4; n++) {
        s16x8 bv2 = *(const s16x8*)&Vs[swz8(n * 16 + l15, g)];
        accO[n] = __builtin_amdgcn_mfma_f32_16x16x32_bf16(ap, bv2, accO[n], 0, 0, 0);
      }
    }
    __syncthreads();                                  // (3) tile done
  }

  // ---- epilogue: O = accO / l ----
#pragma unroll
  for (int n = 0; n < 4; n++) {
    int dd = h * 64 + n * 16 + l15;
#pragma unroll
    for (int j = 0; j < 4; j++) {
      int iq = q0 + wave * 16 + (l4 << 2) + j;
      ctx[(size_t)(b * S + iq) * HID + dd] = f2bf(accO[n][j] / l[j]);
    }
  }
}

// ---------------------------------------------------------------------------
extern "C" void kernel_launch(void* const* d_in, const int* in_sizes, int n_in,
                              void* d_out, int out_size, void* d_ws,
                              size_t ws_size, hipStream_t stream) {
  (void)in_sizes; (void)n_in; (void)out_size; (void)ws_size;
  const int*   tok     = (const int*)d_in[0];
  const int*   seg     = (const int*)d_in[1];
  const float* tok_emb = (const float*)d_in[2];
  const float* seg_emb = (const float*)d_in[3];
  const float* Wq  = (const float*)d_in[4];
  const float* bq  = (const float*)d_in[5];
  const float* Wk  = (const float*)d_in[6];
  const float* bk  = (const float*)d_in[7];
  const float* Wv  = (const float*)d_in[8];
  const float* bv  = (const float*)d_in[9];
  const float* Wo  = (const float*)d_in[10];
  const float* bo  = (const float*)d_in[11];
  const float* Wpk = (const float*)d_in[12];
  const float* Wpq = (const float*)d_in[13];
  const float* rel = (const float*)d_in[14];
  const float* ln1g = (const float*)d_in[15];
  const float* ln1b = (const float*)d_in[16];
  const float* ln2g = (const float*)d_in[17];
  const float* ln2b = (const float*)d_in[18];
  const float* W1  = (const float*)d_in[19];
  const float* b1  = (const float*)d_in[20];
  const float* W2  = (const float*)d_in[21];
  const float* b2  = (const float*)d_in[22];
  const float* lnfg = (const float*)d_in[23];
  const float* lnfb = (const float*)d_in[24];
  float* out = (float*)d_out;

  // ---- workspace layout (~281 MB of ~528 MB) ----
  char* base = (char*)d_ws;
  size_t off = 0;
  auto alloc = [&](size_t bytes) -> void* {
    void* p = base + off;
    off += (bytes + 255) & ~(size_t)255;
    return p;
  };
  const size_t XSZ = (size_t)NTOK * HID;
  float* x = (float*)alloc(XSZ * 4);
  us* qkv16 = (us*)alloc((size_t)NTOK * 2304 * 2);
  us* pkq16 = (us*)alloc((size_t)M2 * 1536 * 2);
  us* vt16  = (us*)alloc(XSZ * 2);
  us* act16 = (us*)alloc(XSZ * 2);
  us* ff16  = (us*)alloc((size_t)NTOK * FF * 2);
  us* rel16 = (us*)alloc((size_t)M2 * HID * 2);
  us* wt6   = (us*)alloc((size_t)6 * HID * HID * 2);
  us* wt1   = (us*)alloc((size_t)HID * FF * 2);
  us* wt2   = (us*)alloc((size_t)HID * FF * 2);
  float* skbuf = (float*)alloc((size_t)2 * NTOK * HID * 4);
  float* bqkv  = (float*)alloc((size_t)L * 2304 * 4);
  us* QP = (us*)alloc((size_t)B * NH * S * 512 * 2);   // 50.33 MB
  us* KP = (us*)alloc((size_t)B * NH * S * 512 * 2);   // 50.33 MB

  const size_t WSQ = (size_t)HID * HID;

  embed_kernel<<<NTOK, 256, 0, stream>>>(tok, seg, tok_emb, seg_emb, x);
  concat_bias<<<(L * 2304 + 255) / 256, 256, 0, stream>>>(bq, bk, bv, bqkv);
  ln_kernel<1><<<NTOK / 4, 256, 0, stream>>>(x, act16, ln1g, ln1b, NTOK);

  for (int l = 0; l < L; l++) {
    // ---- merged weight prep (slots: 0=q 1=k 2=v 3=o 4=pk 5=pq) ----
    weight_prep<<<8832, 256, 0, stream>>>(
        Wq + l * WSQ, Wk + l * WSQ, Wv + l * WSQ, Wo + l * WSQ,
        Wpk + l * WSQ, Wpq + l * WSQ, W1 + (size_t)l * HID * FF,
        W2 + (size_t)l * FF * HID, rel + (size_t)l * M2 * HID,
        wt6, wt1, wt2, rel16);

    // ---- attention ----
    mfma_gemm<128, 64, 1, 0, 0><<<dim3(2304 / 128, NTOK / 128, 1), 256, 0, stream>>>(
        act16, wt6, bqkv + l * 2304, nullptr, qkv16, NTOK, HID, 2304, HID);
    mfma_gemm<64, 32, 1, 0, 0><<<dim3(1536 / 64, M2 / 128, 1), 256, 0, stream>>>(
        rel16, wt6 + 4 * WSQ, nullptr, nullptr, pkq16, M2, HID, 1536, HID);
    transpose_v<<<dim3(S / 32, D / 32, B * NH), 256, 0, stream>>>(qkv16, vt16);
    qpkp_kernel<<<dim3(S / 64, B * NH, 2), 256, 0, stream>>>(
        qkv16, pkq16, QP, KP);
    flash_attn<<<dim3(S / 64, B * NH), 256, 0, stream>>>(
        qkv16, QP, KP, vt16, tok, act16);

    // ---- O-proj: split-K x2 partials + fused (bias + residual + LN2) ----
    mfma_gemm<64, 32, 0, 0, 1><<<dim3(HID / 64, NTOK / 128, 2), 256, 0, stream>>>(
        act16, wt6 + 3 * WSQ, nullptr, nullptr, skbuf, NTOK, HID, HID, HID / 2);
    combine_ln<0><<<NTOK, 256, 0, stream>>>(
        skbuf, x, bo + l * HID, ln2g + l * HID, ln2b + l * HID, act16);

    // ---- feedforward ----
    mfma_gemm<128, 64, 1, 1, 0><<<dim3(FF / 128, NTOK / 128, 1), 256, 0, stream>>>(
        act16, wt1, b1 + l * FF, nullptr, ff16, NTOK, HID, FF, HID);
    mfma_gemm<64, 32, 0, 0, 1><<<dim3(HID / 64, NTOK / 128, 2), 256, 0, stream>>>(
        ff16, wt2, nullptr, nullptr, skbuf, NTOK, FF, HID, FF / 2);
    if (l < L - 1) {
      combine_ln<0><<<NTOK, 256, 0, stream>>>(
          skbuf, x, b2 + l * HID, ln1g + (l + 1) * HID, ln1b + (l + 1) * HID,
          act16);
    } else {
      combine_ln<1><<<NTOK, 256, 0, stream>>>(
          skbuf, x, b2 + l * HID, lnfg, lnfb, out);
    }
  }
}